// Round 1
// baseline (391.580 us; speedup 1.0000x reference)
//
#include <hip/hip_runtime.h>
#include <cmath>
#include <cstdint>

typedef __bf16 bf16;
typedef bf16 bf16x4 __attribute__((ext_vector_type(4)));
typedef bf16 bf16x8 __attribute__((ext_vector_type(8)));
typedef float f32x4 __attribute__((ext_vector_type(4)));
typedef unsigned int u32;
typedef u32 u32x4 __attribute__((ext_vector_type(4)));

#define EPS 1e-5f

__device__ __forceinline__ float clipf(float v) {
    return fminf(fmaxf(v, -10000.0f), 10000.0f);
}
__device__ __forceinline__ float fin0(float v) { return isfinite(v) ? v : 0.0f; }

__device__ __forceinline__ void async_copy16(void* lds, const void* g) {
    __builtin_amdgcn_global_load_lds((__attribute__((address_space(1))) void*)(void*)g,
                                     (__attribute__((address_space(3))) void*)lds,
                                     16, 0, 0);
}

// ================= prep: all weight converts + input rmsnorm, one dispatch =================
// flat grid 15872 blocks x 256 thr.  W1/W3 now written INTERLEAVED (16-row groups) into Wf.
__global__ __launch_bounds__(256) void prep(const float* __restrict__ wq, const float* __restrict__ wk,
                                            const float* __restrict__ wv, const float* __restrict__ wo,
                                            bf16* __restrict__ Wq, bf16* __restrict__ Wk,
                                            bf16* __restrict__ Wv, bf16* __restrict__ Wo,
                                            const float* __restrict__ w1, const float* __restrict__ w3,
                                            bf16* __restrict__ Wf,
                                            const float* __restrict__ w2, bf16* __restrict__ W2p,
                                            const float* __restrict__ x, const float* __restrict__ snw,
                                            bf16* __restrict__ xn) {
    const int bid = blockIdx.x, t = threadIdx.x;
    if (bid < 4096) {
        int z = bid >> 10, r = bid & 1023;
        const float* in = (z == 0) ? wq : (z == 1) ? wk : (z == 2) ? wv : wo;
        bf16* out = (z == 0) ? Wq : (z == 1) ? Wk : (z == 2) ? Wv : Wo;
        f32x4 v = ((const f32x4*)(in + (size_t)r * 1024))[t];
        bf16x4 o = {(bf16)v[0], (bf16)v[1], (bf16)v[2], (bf16)v[3]};
        ((bf16x4*)(out + (size_t)r * 1024))[t] = o;
    } else if (bid < 10752) {
        // interleaved row ri: group g=ri>>5, stream s=(ri>>4)&1, offset o=ri&15
        // logical W1/W3 row = g*16 + o.  stream 0 -> w1, stream 1 -> w3.
        int ri = bid - 4096;
        int lc = ((ri >> 5) << 4) + (ri & 15);
        const float* in = ((ri >> 4) & 1) ? w3 : w1;
        bf16x4 o = {(bf16)0.f, (bf16)0.f, (bf16)0.f, (bf16)0.f};
        if (lc < 3280) {
            f32x4 v = ((const f32x4*)(in + (size_t)lc * 1024))[t];
            o[0] = (bf16)v[0]; o[1] = (bf16)v[1]; o[2] = (bf16)v[2]; o[3] = (bf16)v[3];
        }
        ((bf16x4*)(Wf + (size_t)ri * 1024))[t] = o;
    } else if (bid < 11776) {
        int r = bid - 10752;
        for (int c4 = t * 4; c4 < 3328; c4 += 1024) {
            bf16x4 o = {(bf16)0.f, (bf16)0.f, (bf16)0.f, (bf16)0.f};
            if (c4 + 3 < 3280) {
                f32x4 v = *(const f32x4*)(w2 + (size_t)r * 3280 + c4);
                o[0] = (bf16)v[0]; o[1] = (bf16)v[1]; o[2] = (bf16)v[2]; o[3] = (bf16)v[3];
            } else {
                #pragma unroll
                for (int j = 0; j < 4; ++j)
                    if (c4 + j < 3280) o[j] = (bf16)w2[(size_t)r * 3280 + c4 + j];
            }
            *(bf16x4*)(W2p + (size_t)r * 3328 + c4) = o;
        }
    } else {
        __shared__ float sred[4];
        int row = bid - 11776;
        f32x4 xv = ((const f32x4*)(x + (size_t)row * 1024))[t];
        f32x4 cv;
        cv[0] = clipf(xv[0]); cv[1] = clipf(xv[1]); cv[2] = clipf(xv[2]); cv[3] = clipf(xv[3]);
        float ss = cv[0]*cv[0] + cv[1]*cv[1] + cv[2]*cv[2] + cv[3]*cv[3];
        #pragma unroll
        for (int off = 32; off >= 1; off >>= 1) ss += __shfl_xor(ss, off, 64);
        if ((t & 63) == 0) sred[t >> 6] = ss;
        __syncthreads();
        float tot = sred[0] + sred[1] + sred[2] + sred[3];
        float rms = sqrtf(fmaxf(tot * (1.0f / 1024.0f), EPS) + EPS);
        f32x4 wv_ = ((const f32x4*)snw)[t];
        bf16x4 o;
        o[0] = (bf16)fin0(cv[0] / rms * wv_[0]);
        o[1] = (bf16)fin0(cv[1] / rms * wv_[1]);
        o[2] = (bf16)fin0(cv[2] / rms * wv_[2]);
        o[3] = (bf16)fin0(cv[3] / rms * wv_[3]);
        *(bf16x4*)(xn + (size_t)row * 1024 + t * 4) = o;
    }
}

// ================= QKV GEMM (dbuf), fused head-rmsnorm (q,k), vT epilogue =================
// grid (32, 8, 3), block 256.
__global__ __launch_bounds__(256) void gemm_qkv(const bf16* __restrict__ A,
                                                const bf16* __restrict__ B0,
                                                const bf16* __restrict__ B1,
                                                const bf16* __restrict__ B2,
                                                const float* __restrict__ g0,
                                                const float* __restrict__ g1,
                                                const float* __restrict__ g2,
                                                const float* __restrict__ qnw,
                                                const float* __restrict__ knw,
                                                bf16* __restrict__ C0,
                                                bf16* __restrict__ C1,
                                                bf16* __restrict__ VT) {
    const int z = blockIdx.z;
    const bf16* B = (z == 0) ? B0 : (z == 1) ? B1 : B2;
    const float* bias = (z == 0) ? g0 : (z == 1) ? g1 : g2;
    const float* hw = (z == 0) ? qnw : knw;

    __shared__ __align__(16) bf16 sA[2][128 * 32];
    __shared__ __align__(16) bf16 sB[2][128 * 32];
    const int tid = threadIdx.x;
    const int w = tid >> 6, lane = tid & 63;
    const int m0 = blockIdx.x * 128;
    const int n0 = blockIdx.y * 128;
    const int mwo = (w >> 1) * 64, nwo = (w & 1) * 64;
    const int r16 = lane & 15, quad = lane >> 4;
    const int kreg = quad * 8;
    const int K = 1024, N = 1024;

    f32x4 zero = {0.f, 0.f, 0.f, 0.f};
    f32x4 acc[4][4];
    #pragma unroll
    for (int i = 0; i < 4; ++i)
        #pragma unroll
        for (int j = 0; j < 4; ++j) acc[i][j] = zero;

    const int c0 = tid, c1 = tid + 256;
    const int am0 = c0 >> 2, ak0 = (c0 & 3) << 3;
    const int am1 = c1 >> 2, ak1 = (c1 & 3) << 3;

    {
        async_copy16(&sA[0][c0 * 8], &A[(size_t)(m0 + am0) * K + ak0]);
        async_copy16(&sA[0][c1 * 8], &A[(size_t)(m0 + am1) * K + ak1]);
        async_copy16(&sB[0][c0 * 8], &B[(size_t)(n0 + am0) * K + ak0]);
        async_copy16(&sB[0][c1 * 8], &B[(size_t)(n0 + am1) * K + ak1]);
    }
    for (int kt = 0; kt < 32; ++kt) {
        __syncthreads();
        const int cur = kt & 1, nxt = cur ^ 1;
        if (kt + 1 < 32) {
            const int kb = (kt + 1) << 5;
            async_copy16(&sA[nxt][c0 * 8], &A[(size_t)(m0 + am0) * K + kb + ak0]);
            async_copy16(&sA[nxt][c1 * 8], &A[(size_t)(m0 + am1) * K + kb + ak1]);
            async_copy16(&sB[nxt][c0 * 8], &B[(size_t)(n0 + am0) * K + kb + ak0]);
            async_copy16(&sB[nxt][c1 * 8], &B[(size_t)(n0 + am1) * K + kb + ak1]);
        }
        bf16x8 af[4], bfr[4];
        #pragma unroll
        for (int i = 0; i < 4; ++i) {
            af[i]  = *(const bf16x8*)&sA[cur][(mwo + i * 16 + r16) * 32 + kreg];
            bfr[i] = *(const bf16x8*)&sB[cur][(nwo + i * 16 + r16) * 32 + kreg];
        }
        #pragma unroll
        for (int mi = 0; mi < 4; ++mi)
            #pragma unroll
            for (int ni = 0; ni < 4; ++ni)
                acc[mi][ni] = __builtin_amdgcn_mfma_f32_16x16x32_bf16(af[mi], bfr[ni], acc[mi][ni], 0, 0, 0);
    }

    float bv[4];
    #pragma unroll
    for (int ni = 0; ni < 4; ++ni) bv[ni] = bias[n0 + nwo + ni * 16 + r16];

    if (z < 2) {
        bf16* C = (z == 0) ? C0 : C1;
        float nwv[4];
        #pragma unroll
        for (int ni = 0; ni < 4; ++ni) nwv[ni] = hw[ni * 16 + r16];
        #pragma unroll
        for (int mi = 0; mi < 4; ++mi) {
            #pragma unroll
            for (int r = 0; r < 4; ++r) {
                float v[4], ss = 0.0f;
                #pragma unroll
                for (int ni = 0; ni < 4; ++ni) {
                    v[ni] = clipf(acc[mi][ni][r] + bv[ni]);
                    ss += v[ni] * v[ni];
                }
                ss += __shfl_xor(ss, 1, 64);
                ss += __shfl_xor(ss, 2, 64);
                ss += __shfl_xor(ss, 4, 64);
                ss += __shfl_xor(ss, 8, 64);
                float rms = sqrtf(fmaxf(ss * (1.0f / 64.0f), EPS) + EPS);
                int row = m0 + mwo + mi * 16 + quad * 4 + r;
                #pragma unroll
                for (int ni = 0; ni < 4; ++ni) {
                    int col = n0 + nwo + ni * 16 + r16;
                    C[(size_t)row * N + col] = (bf16)fin0(v[ni] / rms * nwv[ni]);
                }
            }
        }
    } else {
        const int b_ = m0 >> 10;
        const int tokbase = (m0 & 1023) + mwo;
        #pragma unroll
        for (int ni = 0; ni < 4; ++ni) {
            int col = n0 + nwo + ni * 16 + r16;
            int h_ = col >> 6, hd = col & 63;
            bf16* dst = VT + (((size_t)b_ * 16 + h_) * 64 + hd) * 1024;
            #pragma unroll
            for (int mi = 0; mi < 4; ++mi) {
                bf16x4 pack;
                #pragma unroll
                for (int r = 0; r < 4; ++r) pack[r] = (bf16)(acc[mi][ni][r] + bv[ni]);
                *(bf16x4*)&dst[tokbase + mi * 16 + quad * 4] = pack;
            }
        }
    }
}

// ================= windowed causal flash attention, FIXED-MAX softmax (r9) =================
// grid: (L/64, H, B), block 256. q/k: (B,L,H,64); vt: (B,H,64,L).
__global__ __launch_bounds__(256) void attn_win(const bf16* __restrict__ q,
                                                const bf16* __restrict__ k,
                                                const bf16* __restrict__ vt,
                                                const int* __restrict__ winp,
                                                bf16* __restrict__ o) {
    __shared__ __align__(16) bf16 sQ[64 * 64];
    __shared__ __align__(16) bf16 sK[64 * 64];
    __shared__ __align__(16) bf16 sVt[64 * 80];
    __shared__ __align__(16) bf16 sP[64 * 64];
    const int tid = threadIdx.x, w = tid >> 6, lane = tid & 63;
    const int qt = blockIdx.x, h = blockIdx.y, b = blockIdx.z;
    const int q0 = qt * 64;
    const int win = *winp;
    const float scale = 0.125f;
    const int r16 = lane & 15, quad = lane >> 4;

    {
        int qr0 = tid >> 3, col0 = (tid & 7) * 8;
        async_copy16(&sQ[tid * 8], &q[(((size_t)b * 1024 + q0 + qr0) * 16 + h) * 64 + col0]);
        int c1 = tid + 256;
        int qr1 = c1 >> 3, col1 = (c1 & 7) * 8;
        async_copy16(&sQ[c1 * 8], &q[(((size_t)b * 1024 + q0 + qr1) * 16 + h) * 64 + col1]);
    }
    __syncthreads();
    bf16x8 aq0 = *(const bf16x8*)&sQ[(w * 16 + r16) * 64 + quad * 8];
    bf16x8 aq1 = *(const bf16x8*)&sQ[(w * 16 + r16) * 64 + 32 + quad * 8];

    float Lr[4];
    f32x4 zero = {0.f, 0.f, 0.f, 0.f};
    f32x4 accO[4];
    #pragma unroll
    for (int r = 0; r < 4; ++r) Lr[r] = 0.0f;
    #pragma unroll
    for (int nf = 0; nf < 4; ++nf) accO[nf] = zero;

    int lo = q0 - (win - 1); if (lo < 0) lo = 0;
    const int kt0 = lo >> 6;
    const bf16* vth = vt + ((size_t)b * 16 + h) * 64 * 1024;

    for (int kt = kt0; kt <= qt; ++kt) {
        __syncthreads();
        {
            int col0 = (tid & 7) * 8;
            async_copy16(&sK[tid * 8], &k[(((size_t)b * 1024 + kt * 64 + (tid >> 3)) * 16 + h) * 64 + col0]);
            int c1 = tid + 256;
            int col1 = (c1 & 7) * 8;
            async_copy16(&sK[c1 * 8], &k[(((size_t)b * 1024 + kt * 64 + (c1 >> 3)) * 16 + h) * 64 + col1]);
        }
        #pragma unroll
        for (int c = tid; c < 512; c += 256) {
            int hd = c >> 3, koff = (c & 7) * 8;
            *(u32x4*)&sVt[hd * 80 + koff] = *(const u32x4*)&vth[(size_t)hd * 1024 + kt * 64 + koff];
        }
        __syncthreads();

        f32x4 sf[4];
        #pragma unroll
        for (int nf = 0; nf < 4; ++nf) {
            bf16x8 bk0 = *(const bf16x8*)&sK[(nf * 16 + r16) * 64 + quad * 8];
            bf16x8 bk1 = *(const bf16x8*)&sK[(nf * 16 + r16) * 64 + 32 + quad * 8];
            f32x4 accS = zero;
            accS = __builtin_amdgcn_mfma_f32_16x16x32_bf16(aq0, bk0, accS, 0, 0, 0);
            accS = __builtin_amdgcn_mfma_f32_16x16x32_bf16(aq1, bk1, accS, 0, 0, 0);
            sf[nf] = accS;
        }

        #pragma unroll
        for (int r = 0; r < 4; ++r) {
            int i = q0 + w * 16 + quad * 4 + r;
            float ps = 0.0f;
            #pragma unroll
            for (int nf = 0; nf < 4; ++nf) {
                int j = kt * 64 + nf * 16 + r16;
                bool ok = (j <= i) && (i - j < win);
                float pv = ok ? __expf(sf[nf][r] * scale - 8.0f) : 0.0f;
                ps += pv;
                sP[(w * 16 + quad * 4 + r) * 64 + nf * 16 + r16] = (bf16)pv;
            }
            Lr[r] += ps;
        }
        __syncthreads();

        bf16x8 ap0 = *(const bf16x8*)&sP[(w * 16 + r16) * 64 + quad * 8];
        bf16x8 ap1 = *(const bf16x8*)&sP[(w * 16 + r16) * 64 + 32 + quad * 8];
        #pragma unroll
        for (int nf = 0; nf < 4; ++nf) {
            bf16x8 bv0 = *(const bf16x8*)&sVt[(nf * 16 + r16) * 80 + quad * 8];
            bf16x8 bv1 = *(const bf16x8*)&sVt[(nf * 16 + r16) * 80 + 32 + quad * 8];
            accO[nf] = __builtin_amdgcn_mfma_f32_16x16x32_bf16(ap0, bv0, accO[nf], 0, 0, 0);
            accO[nf] = __builtin_amdgcn_mfma_f32_16x16x32_bf16(ap1, bv1, accO[nf], 0, 0, 0);
        }
    }

    #pragma unroll
    for (int r = 0; r < 4; ++r) {
        float l = Lr[r];
        l += __shfl_xor(l, 1, 64);
        l += __shfl_xor(l, 2, 64);
        l += __shfl_xor(l, 4, 64);
        l += __shfl_xor(l, 8, 64);
        float inv = (l > 0.0f) ? 1.0f / l : 0.0f;
        int row = q0 + w * 16 + quad * 4 + r;
        #pragma unroll
        for (int nf = 0; nf < 4; ++nf) {
            float ov = fin0(accO[nf][r] * inv);
            o[(((size_t)b * 1024 + row) * 16 + h) * 64 + nf * 16 + r16] = (bf16)ov;
        }
    }
}

// ================= split-K=2 GEMM, 256x128 tile, 8 waves -> f32 partials =================
__global__ __launch_bounds__(512) void gemm_sk2(const bf16* __restrict__ A,
                                                const bf16* __restrict__ B,
                                                float* __restrict__ P,
                                                int K, int Kh) {
    __shared__ __align__(16) bf16 sA[2][256 * 32];
    __shared__ __align__(16) bf16 sB[2][128 * 32];
    const int tid = threadIdx.x;
    const int w = tid >> 6, lane = tid & 63;
    const int m0 = blockIdx.x * 256, n0 = blockIdx.y * 128;
    const int mwo = (w & 3) * 64, nwo = (w >> 2) * 64;
    const int r16 = lane & 15, quad = lane >> 4, kreg = quad * 8;
    const int kbase = blockIdx.z * Kh;
    const int N = 1024;

    const int ar0 = tid >> 2,        ak0 = (tid & 3) << 3;
    const int c1 = tid + 512;
    const int ar1 = c1 >> 2,         ak1 = (c1 & 3) << 3;
    const int br = tid >> 2,         bk = (tid & 3) << 3;

    f32x4 zero = {0.f, 0.f, 0.f, 0.f};
    f32x4 acc[4][4];
    #pragma unroll
    for (int i = 0; i < 4; ++i)
        #pragma unroll
        for (int j = 0; j < 4; ++j) acc[i][j] = zero;

    {
        async_copy16(&sA[0][tid * 8], &A[(size_t)(m0 + ar0) * K + kbase + ak0]);
        async_copy16(&sA[0][c1 * 8],  &A[(size_t)(m0 + ar1) * K + kbase + ak1]);
        async_copy16(&sB[0][tid * 8], &B[(size_t)(n0 + br) * K + kbase + bk]);
    }
    const int kIters = Kh >> 5;
    for (int kt = 0; kt < kIters; ++kt) {
        __syncthreads();
        const int cur = kt & 1, nxt = cur ^ 1;
        if (kt + 1 < kIters) {
            const int kb = kbase + ((kt + 1) << 5);
            async_copy16(&sA[nxt][tid * 8], &A[(size_t)(m0 + ar0) * K + kb + ak0]);
            async_copy16(&sA[nxt][c1 * 8],  &A[(size_t)(m0 + ar1) * K + kb + ak1]);
            async_copy16(&sB[nxt][tid * 8], &B[(size_t)(n0 + br) * K + kb + bk]);
        }
        bf16x8 af[4], bfr[4];
        #pragma unroll
        for (int i = 0; i < 4; ++i) {
            af[i]  = *(const bf16x8*)&sA[cur][(mwo + i * 16 + r16) * 32 + kreg];
            bfr[i] = *(const bf16x8*)&sB[cur][(nwo + i * 16 + r16) * 32 + kreg];
        }
        #pragma unroll
        for (int mi = 0; mi < 4; ++mi)
            #pragma unroll
            for (int ni = 0; ni < 4; ++ni)
                acc[mi][ni] = __builtin_amdgcn_mfma_f32_16x16x32_bf16(af[mi], bfr[ni], acc[mi][ni], 0, 0, 0);
    }

    float* Pz = P + (size_t)blockIdx.z * 4096 * 1024;
    #pragma unroll
    for (int mi = 0; mi < 4; ++mi)
        #pragma unroll
        for (int ni = 0; ni < 4; ++ni) {
            int col = n0 + nwo + ni * 16 + r16;
            #pragma unroll
            for (int r = 0; r < 4; ++r) {
                int row = m0 + mwo + mi * 16 + quad * 4 + r;
                Pz[(size_t)row * N + col] = acc[mi][ni][r];
            }
        }
}

// ================= resid+norm (dual f32 partials) =================
template <bool EMIT>
__global__ __launch_bounds__(512) void resid_norm(const float* __restrict__ xres,
                                                  const float* __restrict__ p0,
                                                  const float* __restrict__ p1,
                                                  const float* __restrict__ bias,
                                                  const float* __restrict__ wpost,
                                                  const float* __restrict__ wnext,
                                                  float* __restrict__ hout,
                                                  bf16* __restrict__ hnout) {
    __shared__ float sred[8];
    const int tid = threadIdx.x;
    const int grp = tid >> 8, t = tid & 255;
    const int w4 = (tid >> 6) & 3;
    for (int it = 0; it < 4; ++it) {
        int row = it * 1024 + blockIdx.x * 2 + grp;
        f32x4 a0 = ((const f32x4*)(p0 + (size_t)row * 1024))[t];
        f32x4 a1 = ((const f32x4*)(p1 + (size_t)row * 1024))[t];
        f32x4 bv = ((const f32x4*)bias)[t];
        f32x4 af;
        af[0] = clipf(a0[0] + a1[0] + bv[0]);
        af[1] = clipf(a0[1] + a1[1] + bv[1]);
        af[2] = clipf(a0[2] + a1[2] + bv[2]);
        af[3] = clipf(a0[3] + a1[3] + bv[3]);
        float ss = af[0]*af[0] + af[1]*af[1] + af[2]*af[2] + af[3]*af[3];
        #pragma unroll
        for (int off = 32; off >= 1; off >>= 1) ss += __shfl_xor(ss, off, 64);
        __syncthreads();
        if ((tid & 63) == 0) sred[grp * 4 + w4] = ss;
        __syncthreads();
        float tot = sred[grp*4+0] + sred[grp*4+1] + sred[grp*4+2] + sred[grp*4+3];
        float rms1 = sqrtf(fmaxf(tot * (1.0f / 1024.0f), EPS) + EPS);
        f32x4 xv = ((const f32x4*)(xres + (size_t)row * 1024))[t];
        f32x4 wp = ((const f32x4*)wpost)[t];
        f32x4 hv;
        hv[0] = xv[0] + fin0(af[0] / rms1 * wp[0]);
        hv[1] = xv[1] + fin0(af[1] / rms1 * wp[1]);
        hv[2] = xv[2] + fin0(af[2] / rms1 * wp[2]);
        hv[3] = xv[3] + fin0(af[3] / rms1 * wp[3]);
        ((f32x4*)(hout + (size_t)row * 1024))[t] = hv;
        if (EMIT) {
            f32x4 cv;
            cv[0] = clipf(hv[0]); cv[1] = clipf(hv[1]); cv[2] = clipf(hv[2]); cv[3] = clipf(hv[3]);
            float ss2 = cv[0]*cv[0] + cv[1]*cv[1] + cv[2]*cv[2] + cv[3]*cv[3];
            #pragma unroll
            for (int off = 32; off >= 1; off >>= 1) ss2 += __shfl_xor(ss2, off, 64);
            __syncthreads();
            if ((tid & 63) == 0) sred[grp * 4 + w4] = ss2;
            __syncthreads();
            float tot2 = sred[grp*4+0] + sred[grp*4+1] + sred[grp*4+2] + sred[grp*4+3];
            float rms2 = sqrtf(fmaxf(tot2 * (1.0f / 1024.0f), EPS) + EPS);
            f32x4 wn = ((const f32x4*)wnext)[t];
            bf16x4 o;
            o[0] = (bf16)fin0(cv[0] / rms2 * wn[0]);
            o[1] = (bf16)fin0(cv[1] / rms2 * wn[1]);
            o[2] = (bf16)fin0(cv[2] / rms2 * wn[2]);
            o[3] = (bf16)fin0(cv[3] / rms2 * wn[3]);
            *(bf16x4*)(hnout + (size_t)row * 1024 + t * 4) = o;
        }
    }
}

// ================= FFN1: 256x256-tile phase-split GEMM (T2+T3+T4+T5), swiglu epilogue ======
// A: hn [4096][1024] bf16. Wf: interleaved W1/W3 [6656][1024] bf16 (16-row groups).
// grid 416 (16 m-tiles x 26 n-tiles, XCD-swizzled), block 512 (8 waves = 2M x 4N).
// LDS 128 KiB: sA[2 dbuf][2 half][128x64], sB likewise. BK=64, 16 K-tiles.
// Schedule per K-tile t (4 phases, 16 MFMA/wave each between raw s_barriers):
//   ph0: stage A(t+1)->sA[nxt]; s_waitcnt vmcnt(8) (counted, never 0 until tail);
//        read B frags (regs, whole tile) + A frags m0/m1; MFMA.
//   ph1: stage B-half0(t+2) into sB[cur] (B[cur] reads finished at ph0); A m2/m3; MFMA.
//   ph2: stage B-half1(t+2);                                             A m4/m5; MFMA.
//   ph3: (no barrier)                                                    A m6/m7; MFMA.
// LDS swizzle: physical 16B slot = kslot ^ (row&7); gload_lds stays linear, the global
// SOURCE address is pre-swizzled (m173 pattern) -> conflict-free ds_read_b128.
template <int MB>
__device__ __forceinline__ void mphase(const bf16* Ah, const bf16x8 (&breg)[4][2],
                                       f32x4 (&acc)[8][4], int r16, int koff0, int koff1) {
    const bf16* pa0 = &Ah[(MB * 16 + r16) * 64];
    const bf16* pa1 = &Ah[((MB + 1) * 16 + r16) * 64];
    bf16x8 a00 = *(const bf16x8*)&pa0[koff0];
    bf16x8 a01 = *(const bf16x8*)&pa0[koff1];
    bf16x8 a10 = *(const bf16x8*)&pa1[koff0];
    bf16x8 a11 = *(const bf16x8*)&pa1[koff1];
    __builtin_amdgcn_s_setprio(1);
    #pragma unroll
    for (int n = 0; n < 4; ++n) {
        acc[MB][n]     = __builtin_amdgcn_mfma_f32_16x16x32_bf16(a00, breg[n][0], acc[MB][n], 0, 0, 0);
        acc[MB][n]     = __builtin_amdgcn_mfma_f32_16x16x32_bf16(a01, breg[n][1], acc[MB][n], 0, 0, 0);
        acc[MB + 1][n] = __builtin_amdgcn_mfma_f32_16x16x32_bf16(a10, breg[n][0], acc[MB + 1][n], 0, 0, 0);
        acc[MB + 1][n] = __builtin_amdgcn_mfma_f32_16x16x32_bf16(a11, breg[n][1], acc[MB + 1][n], 0, 0, 0);
    }
    __builtin_amdgcn_s_setprio(0);
}

__global__ __launch_bounds__(512, 2) void gemm_ffn1_8ph(const bf16* __restrict__ A,
                                                        const bf16* __restrict__ Wf,
                                                        const float* __restrict__ b1,
                                                        const float* __restrict__ b3,
                                                        bf16* __restrict__ G) {
    __shared__ __align__(16) bf16 sA[2][2][128 * 64];
    __shared__ __align__(16) bf16 sB[2][2][128 * 64];
    const int tid = threadIdx.x;
    const int w = tid >> 6, lane = tid & 63;
    const int wr = w >> 2, wc = w & 3;
    const int r16 = lane & 15, quad = lane >> 4;

    // XCD swizzle (416 % 8 == 0, bijective)
    const int flat = blockIdx.x;
    const int swb = (flat & 7) * 52 + (flat >> 3);
    const int bm = swb & 15, bn = swb >> 4;
    const int m0 = bm * 256;
    const int n0i = bn * 256;

    const int swz = r16 & 7;
    const int koff0 = ((quad ^ swz) << 3);
    const int koff1 = (((quad + 4) ^ swz) << 3);

    // staging precompute: thread covers rows sr0 and sr0+64 of a 128-row half
    const int sr0 = tid >> 3, sr1 = sr0 + 64;
    const int sk0 = (((tid & 7) ^ (sr0 & 7)) << 3);  // pre-swizzled source k-slot (bf16 elems)

    const bf16* aSrc0 = A + (size_t)m0 * 1024;
    const bf16* aSrc1 = A + (size_t)(m0 + 128) * 1024;
    const bf16* bSrc0 = Wf + (size_t)n0i * 1024;
    const bf16* bSrc1 = Wf + (size_t)(n0i + 128) * 1024;

#define STAGE(dst, src, ktile) do {                                                        \
        async_copy16(&(dst)[tid * 8],         (src) + (size_t)sr0 * 1024 + (ktile) * 64 + sk0); \
        async_copy16(&(dst)[(tid + 512) * 8], (src) + (size_t)sr1 * 1024 + (ktile) * 64 + sk0); \
    } while (0)

    f32x4 acc[8][4];
    #pragma unroll
    for (int i = 0; i < 8; ++i)
        #pragma unroll
        for (int j = 0; j < 4; ++j) acc[i][j] = (f32x4){0.f, 0.f, 0.f, 0.f};

    // prologue: B(0), A(0), B(1)  (12 gload_lds in flight)
    STAGE(sB[0][0], bSrc0, 0); STAGE(sB[0][1], bSrc1, 0);
    STAGE(sA[0][0], aSrc0, 0); STAGE(sA[0][1], aSrc1, 0);
    STAGE(sB[1][0], bSrc0, 1); STAGE(sB[1][1], bSrc1, 1);

    for (int t = 0; t < 16; ++t) {
        const int cur = t & 1, nxt = cur ^ 1;
        const bf16* Ah = &sA[cur][wr][0];
        const bf16* Bh = &sB[cur][wc >> 1][0];
        const int rbB = (wc & 1) << 6;
        bf16x8 breg[4][2];

        // ---- phase 0 ----
        __builtin_amdgcn_s_barrier();
        if (t + 1 < 16) {
            STAGE(sA[nxt][0], aSrc0, t + 1);
            STAGE(sA[nxt][1], aSrc1, t + 1);
        }
        if (t == 15) { asm volatile("s_waitcnt vmcnt(0)" ::: "memory"); }
        else         { asm volatile("s_waitcnt vmcnt(8)" ::: "memory"); }
        #pragma unroll
        for (int n = 0; n < 4; ++n) {
            const bf16* p = &Bh[(rbB + n * 16 + r16) * 64];
            breg[n][0] = *(const bf16x8*)&p[koff0];
            breg[n][1] = *(const bf16x8*)&p[koff1];
        }
        mphase<0>(Ah, breg, acc, r16, koff0, koff1);

        // ---- phase 1 ----
        __builtin_amdgcn_s_barrier();
        if (t + 2 < 16) STAGE(sB[cur][0], bSrc0, t + 2);
        mphase<2>(Ah, breg, acc, r16, koff0, koff1);

        // ---- phase 2 ----
        __builtin_amdgcn_s_barrier();
        if (t + 2 < 16) STAGE(sB[cur][1], bSrc1, t + 2);
        mphase<4>(Ah, breg, acc, r16, koff0, koff1);

        // ---- phase 3 (no barrier) ----
        mphase<6>(Ah, breg, acc, r16, koff0, koff1);
    }
#undef STAGE

    // swiglu epilogue: frag n even = z1, n odd = z3 (16-row interleave of Wf);
    // pair p=(0,1),(2,3) -> output col (bn*8 + wc*2 + p)*16 + r16
    #pragma unroll
    for (int m = 0; m < 8; ++m) {
        #pragma unroll
        for (int p = 0; p < 2; ++p) {
            int col = (bn * 8 + wc * 2 + p) * 16 + r16;
            float bb1 = (col < 3280) ? b1[col] : 0.0f;
            float bb3 = (col < 3280) ? b3[col] : 0.0f;
            #pragma unroll
            for (int rr = 0; rr < 4; ++rr) {
                int row = m0 + wr * 128 + m * 16 + quad * 4 + rr;
                float z1 = acc[m][2 * p][rr] + bb1;
                float z3 = acc[m][2 * p + 1][rr] + bb3;
                float s = z1 / (1.0f + __expf(-z1));
                G[(size_t)row * 3328 + col] = (bf16)(s * z3);
            }
        }
    }
}

extern "C" void kernel_launch(void* const* d_in, const int* in_sizes, int n_in,
                              void* d_out, int out_size, void* d_ws, size_t ws_size,
                              hipStream_t stream) {
    const float* x       = (const float*)d_in[0];
    const float* wq_w    = (const float*)d_in[1];
    const float* wq_b    = (const float*)d_in[2];
    const float* wk_w    = (const float*)d_in[3];
    const float* wk_b    = (const float*)d_in[4];
    const float* wv_w    = (const float*)d_in[5];
    const float* wv_b    = (const float*)d_in[6];
    const float* wo_w    = (const float*)d_in[7];
    const float* wo_b    = (const float*)d_in[8];
    const float* q_norm_w= (const float*)d_in[9];
    const float* k_norm_w= (const float*)d_in[10];
    const float* seq_norm_w      = (const float*)d_in[11];
    const float* seq_post_norm_w = (const float*)d_in[12];
    const float* ffn_norm_w      = (const float*)d_in[13];
    const float* ffn_post_norm_w = (const float*)d_in[14];
    const float* w1_w    = (const float*)d_in[15];
    const float* w1_b    = (const float*)d_in[16];
    const float* w2_w    = (const float*)d_in[17];
    const float* w2_b    = (const float*)d_in[18];
    const float* w3_w    = (const float*)d_in[19];
    const float* w3_b    = (const float*)d_in[20];
    const int*   winp    = (const int*)d_in[21];
    float* out = (float*)d_out;

    const size_t SZ_W   = 2097152;    // 1024*1024*2
    const size_t SZ_WP  = 6815744;    // 3328*1024*2
    const size_t SZ_ACT = 8388608;    // 4096*1024*2
    const size_t SZ_H   = 16777216;   // 4096*1024*4
    const size_t SZ_P   = 33554432;   // 2*4096*1024*4 (split-K partials)

    char* p = (char*)d_ws;
    bf16* Wq  = (bf16*)p; p += SZ_W;
    bf16* Wk  = (bf16*)p; p += SZ_W;
    bf16* Wv  = (bf16*)p; p += SZ_W;
    bf16* Wo  = (bf16*)p; p += SZ_W;
    bf16* Wfp = (bf16*)p; p += 2 * SZ_WP;   // 6656x1024 interleaved W1/W3
    bf16* W2p = (bf16*)p; p += SZ_WP;
    float* h  = (float*)p; p += SZ_H;
    bf16* hn  = (bf16*)p; p += SZ_ACT;
    float* part = (float*)p; p += SZ_P;
    float* part1 = part + (size_t)4096 * 1024;
    char* regionA = p;  // aliased: attn-phase buffers, later g
    bf16* xn    = (bf16*)(regionA);
    bf16* qb    = (bf16*)(regionA + 1 * SZ_ACT);
    bf16* kb    = (bf16*)(regionA + 2 * SZ_ACT);
    bf16* vtb   = (bf16*)(regionA + 3 * SZ_ACT);
    bf16* attnb = (bf16*)(regionA + 4 * SZ_ACT);
    bf16* g     = (bf16*)(regionA);   // 27.3 MB; reuses xn..vtb after attention phase

    // 1) prep: all converts (W1/W3 interleaved) + rmsnorm(x)
    prep<<<dim3(15872), dim3(256), 0, stream>>>(wq_w, wk_w, wv_w, wo_w, Wq, Wk, Wv, Wo,
                                                w1_w, w3_w, Wfp, w2_w, W2p,
                                                x, seq_norm_w, xn);

    // 2) QKV projections; q,k head-normed; v transposed
    gemm_qkv<<<dim3(32, 8, 3), dim3(256), 0, stream>>>(xn, Wq, Wk, Wv, wq_b, wk_b, wv_b,
                                                       q_norm_w, k_norm_w, qb, kb, vtb);

    // 3) windowed causal attention (fixed-max softmax)
    attn_win<<<dim3(16, 16, 4), dim3(256), 0, stream>>>(qb, kb, vtb, winp, attnb);

    // 4) O-projection: 256x128 split-K=2 -> f32 partials (K=1024, Kh=512)
    gemm_sk2<<<dim3(16, 8, 2), dim3(512), 0, stream>>>(attnb, Wo, part, 1024, 512);

    // 5) h = x + rmsnorm(p0+p1+wo_b, seq_post); hn = rmsnorm(h, ffn_norm)
    resid_norm<true><<<dim3(512), dim3(512), 0, stream>>>(x, part, part1, wo_b,
                                                          seq_post_norm_w, ffn_norm_w, h, hn);

    // 6) fused FFN1: 256x256 phase-split pipeline, interleaved W1/W3, swiglu epilogue
    gemm_ffn1_8ph<<<dim3(416), dim3(512), 0, stream>>>(hn, Wfp, w1_b, w3_b, g);

    // 7) FFN2: 256x128 split-K=2 -> f32 partials (K=3328, Kh=1664, 52 iters)
    gemm_sk2<<<dim3(16, 8, 2), dim3(512), 0, stream>>>(g, W2p, part, 3328, 1664);

    // 8) out = h + rmsnorm(p0+p1+w2_b, ffn_post)
    resid_norm<false><<<dim3(512), dim3(512), 0, stream>>>(h, part, part1, w2_b,
                                                           ffn_post_norm_w, nullptr, out, nullptr);
}

// Round 2
// 387.225 us; speedup vs baseline: 1.0112x; 1.0112x over previous
//
#include <hip/hip_runtime.h>
#include <cmath>
#include <cstdint>

typedef __bf16 bf16;
typedef bf16 bf16x4 __attribute__((ext_vector_type(4)));
typedef bf16 bf16x8 __attribute__((ext_vector_type(8)));
typedef float f32x4 __attribute__((ext_vector_type(4)));
typedef unsigned int u32;
typedef u32 u32x4 __attribute__((ext_vector_type(4)));

#define EPS 1e-5f

__device__ __forceinline__ float clipf(float v) {
    return fminf(fmaxf(v, -10000.0f), 10000.0f);
}
__device__ __forceinline__ float fin0(float v) { return isfinite(v) ? v : 0.0f; }

__device__ __forceinline__ void async_copy16(void* lds, const void* g) {
    __builtin_amdgcn_global_load_lds((__attribute__((address_space(1))) void*)(void*)g,
                                     (__attribute__((address_space(3))) void*)lds,
                                     16, 0, 0);
}

// ================= prep: all weight converts + input rmsnorm, one dispatch =================
// flat grid 15872 blocks x 256 thr.  W1/W3 written INTERLEAVED (16-row groups) into Wf.
__global__ __launch_bounds__(256) void prep(const float* __restrict__ wq, const float* __restrict__ wk,
                                            const float* __restrict__ wv, const float* __restrict__ wo,
                                            bf16* __restrict__ Wq, bf16* __restrict__ Wk,
                                            bf16* __restrict__ Wv, bf16* __restrict__ Wo,
                                            const float* __restrict__ w1, const float* __restrict__ w3,
                                            bf16* __restrict__ Wf,
                                            const float* __restrict__ w2, bf16* __restrict__ W2p,
                                            const float* __restrict__ x, const float* __restrict__ snw,
                                            bf16* __restrict__ xn) {
    const int bid = blockIdx.x, t = threadIdx.x;
    if (bid < 4096) {
        int z = bid >> 10, r = bid & 1023;
        const float* in = (z == 0) ? wq : (z == 1) ? wk : (z == 2) ? wv : wo;
        bf16* out = (z == 0) ? Wq : (z == 1) ? Wk : (z == 2) ? Wv : Wo;
        f32x4 v = ((const f32x4*)(in + (size_t)r * 1024))[t];
        bf16x4 o = {(bf16)v[0], (bf16)v[1], (bf16)v[2], (bf16)v[3]};
        ((bf16x4*)(out + (size_t)r * 1024))[t] = o;
    } else if (bid < 10752) {
        // interleaved row ri: group g=ri>>5, stream s=(ri>>4)&1, offset o=ri&15
        // logical W1/W3 row = g*16 + o.  stream 0 -> w1, stream 1 -> w3.
        int ri = bid - 4096;
        int lc = ((ri >> 5) << 4) + (ri & 15);
        const float* in = ((ri >> 4) & 1) ? w3 : w1;
        bf16x4 o = {(bf16)0.f, (bf16)0.f, (bf16)0.f, (bf16)0.f};
        if (lc < 3280) {
            f32x4 v = ((const f32x4*)(in + (size_t)lc * 1024))[t];
            o[0] = (bf16)v[0]; o[1] = (bf16)v[1]; o[2] = (bf16)v[2]; o[3] = (bf16)v[3];
        }
        ((bf16x4*)(Wf + (size_t)ri * 1024))[t] = o;
    } else if (bid < 11776) {
        int r = bid - 10752;
        for (int c4 = t * 4; c4 < 3328; c4 += 1024) {
            bf16x4 o = {(bf16)0.f, (bf16)0.f, (bf16)0.f, (bf16)0.f};
            if (c4 + 3 < 3280) {
                f32x4 v = *(const f32x4*)(w2 + (size_t)r * 3280 + c4);
                o[0] = (bf16)v[0]; o[1] = (bf16)v[1]; o[2] = (bf16)v[2]; o[3] = (bf16)v[3];
            } else {
                #pragma unroll
                for (int j = 0; j < 4; ++j)
                    if (c4 + j < 3280) o[j] = (bf16)w2[(size_t)r * 3280 + c4 + j];
            }
            *(bf16x4*)(W2p + (size_t)r * 3328 + c4) = o;
        }
    } else {
        __shared__ float sred[4];
        int row = bid - 11776;
        f32x4 xv = ((const f32x4*)(x + (size_t)row * 1024))[t];
        f32x4 cv;
        cv[0] = clipf(xv[0]); cv[1] = clipf(xv[1]); cv[2] = clipf(xv[2]); cv[3] = clipf(xv[3]);
        float ss = cv[0]*cv[0] + cv[1]*cv[1] + cv[2]*cv[2] + cv[3]*cv[3];
        #pragma unroll
        for (int off = 32; off >= 1; off >>= 1) ss += __shfl_xor(ss, off, 64);
        if ((t & 63) == 0) sred[t >> 6] = ss;
        __syncthreads();
        float tot = sred[0] + sred[1] + sred[2] + sred[3];
        float rms = sqrtf(fmaxf(tot * (1.0f / 1024.0f), EPS) + EPS);
        f32x4 wv_ = ((const f32x4*)snw)[t];
        bf16x4 o;
        o[0] = (bf16)fin0(cv[0] / rms * wv_[0]);
        o[1] = (bf16)fin0(cv[1] / rms * wv_[1]);
        o[2] = (bf16)fin0(cv[2] / rms * wv_[2]);
        o[3] = (bf16)fin0(cv[3] / rms * wv_[3]);
        *(bf16x4*)(xn + (size_t)row * 1024 + t * 4) = o;
    }
}

// ================= QKV GEMM (dbuf), fused head-rmsnorm (q,k), vT epilogue =================
// grid (32, 8, 3), block 256.
__global__ __launch_bounds__(256) void gemm_qkv(const bf16* __restrict__ A,
                                                const bf16* __restrict__ B0,
                                                const bf16* __restrict__ B1,
                                                const bf16* __restrict__ B2,
                                                const float* __restrict__ g0,
                                                const float* __restrict__ g1,
                                                const float* __restrict__ g2,
                                                const float* __restrict__ qnw,
                                                const float* __restrict__ knw,
                                                bf16* __restrict__ C0,
                                                bf16* __restrict__ C1,
                                                bf16* __restrict__ VT) {
    const int z = blockIdx.z;
    const bf16* B = (z == 0) ? B0 : (z == 1) ? B1 : B2;
    const float* bias = (z == 0) ? g0 : (z == 1) ? g1 : g2;
    const float* hw = (z == 0) ? qnw : knw;

    __shared__ __align__(16) bf16 sA[2][128 * 32];
    __shared__ __align__(16) bf16 sB[2][128 * 32];
    const int tid = threadIdx.x;
    const int w = tid >> 6, lane = tid & 63;
    const int m0 = blockIdx.x * 128;
    const int n0 = blockIdx.y * 128;
    const int mwo = (w >> 1) * 64, nwo = (w & 1) * 64;
    const int r16 = lane & 15, quad = lane >> 4;
    const int kreg = quad * 8;
    const int K = 1024, N = 1024;

    f32x4 zero = {0.f, 0.f, 0.f, 0.f};
    f32x4 acc[4][4];
    #pragma unroll
    for (int i = 0; i < 4; ++i)
        #pragma unroll
        for (int j = 0; j < 4; ++j) acc[i][j] = zero;

    const int c0 = tid, c1 = tid + 256;
    const int am0 = c0 >> 2, ak0 = (c0 & 3) << 3;
    const int am1 = c1 >> 2, ak1 = (c1 & 3) << 3;

    {
        async_copy16(&sA[0][c0 * 8], &A[(size_t)(m0 + am0) * K + ak0]);
        async_copy16(&sA[0][c1 * 8], &A[(size_t)(m0 + am1) * K + ak1]);
        async_copy16(&sB[0][c0 * 8], &B[(size_t)(n0 + am0) * K + ak0]);
        async_copy16(&sB[0][c1 * 8], &B[(size_t)(n0 + am1) * K + ak1]);
    }
    for (int kt = 0; kt < 32; ++kt) {
        __syncthreads();
        const int cur = kt & 1, nxt = cur ^ 1;
        if (kt + 1 < 32) {
            const int kb = (kt + 1) << 5;
            async_copy16(&sA[nxt][c0 * 8], &A[(size_t)(m0 + am0) * K + kb + ak0]);
            async_copy16(&sA[nxt][c1 * 8], &A[(size_t)(m0 + am1) * K + kb + ak1]);
            async_copy16(&sB[nxt][c0 * 8], &B[(size_t)(n0 + am0) * K + kb + ak0]);
            async_copy16(&sB[nxt][c1 * 8], &B[(size_t)(n0 + am1) * K + kb + ak1]);
        }
        bf16x8 af[4], bfr[4];
        #pragma unroll
        for (int i = 0; i < 4; ++i) {
            af[i]  = *(const bf16x8*)&sA[cur][(mwo + i * 16 + r16) * 32 + kreg];
            bfr[i] = *(const bf16x8*)&sB[cur][(nwo + i * 16 + r16) * 32 + kreg];
        }
        #pragma unroll
        for (int mi = 0; mi < 4; ++mi)
            #pragma unroll
            for (int ni = 0; ni < 4; ++ni)
                acc[mi][ni] = __builtin_amdgcn_mfma_f32_16x16x32_bf16(af[mi], bfr[ni], acc[mi][ni], 0, 0, 0);
    }

    float bv[4];
    #pragma unroll
    for (int ni = 0; ni < 4; ++ni) bv[ni] = bias[n0 + nwo + ni * 16 + r16];

    if (z < 2) {
        bf16* C = (z == 0) ? C0 : C1;
        float nwv[4];
        #pragma unroll
        for (int ni = 0; ni < 4; ++ni) nwv[ni] = hw[ni * 16 + r16];
        #pragma unroll
        for (int mi = 0; mi < 4; ++mi) {
            #pragma unroll
            for (int r = 0; r < 4; ++r) {
                float v[4], ss = 0.0f;
                #pragma unroll
                for (int ni = 0; ni < 4; ++ni) {
                    v[ni] = clipf(acc[mi][ni][r] + bv[ni]);
                    ss += v[ni] * v[ni];
                }
                ss += __shfl_xor(ss, 1, 64);
                ss += __shfl_xor(ss, 2, 64);
                ss += __shfl_xor(ss, 4, 64);
                ss += __shfl_xor(ss, 8, 64);
                float rms = sqrtf(fmaxf(ss * (1.0f / 64.0f), EPS) + EPS);
                int row = m0 + mwo + mi * 16 + quad * 4 + r;
                #pragma unroll
                for (int ni = 0; ni < 4; ++ni) {
                    int col = n0 + nwo + ni * 16 + r16;
                    C[(size_t)row * N + col] = (bf16)fin0(v[ni] / rms * nwv[ni]);
                }
            }
        }
    } else {
        const int b_ = m0 >> 10;
        const int tokbase = (m0 & 1023) + mwo;
        #pragma unroll
        for (int ni = 0; ni < 4; ++ni) {
            int col = n0 + nwo + ni * 16 + r16;
            int h_ = col >> 6, hd = col & 63;
            bf16* dst = VT + (((size_t)b_ * 16 + h_) * 64 + hd) * 1024;
            #pragma unroll
            for (int mi = 0; mi < 4; ++mi) {
                bf16x4 pack;
                #pragma unroll
                for (int r = 0; r < 4; ++r) pack[r] = (bf16)(acc[mi][ni][r] + bv[ni]);
                *(bf16x4*)&dst[tokbase + mi * 16 + quad * 4] = pack;
            }
        }
    }
}

// ================= windowed causal flash attention, FIXED-MAX softmax (r9) =================
// grid: (L/64, H, B), block 256. q/k: (B,L,H,64); vt: (B,H,64,L).
__global__ __launch_bounds__(256) void attn_win(const bf16* __restrict__ q,
                                                const bf16* __restrict__ k,
                                                const bf16* __restrict__ vt,
                                                const int* __restrict__ winp,
                                                bf16* __restrict__ o) {
    __shared__ __align__(16) bf16 sQ[64 * 64];
    __shared__ __align__(16) bf16 sK[64 * 64];
    __shared__ __align__(16) bf16 sVt[64 * 80];
    __shared__ __align__(16) bf16 sP[64 * 64];
    const int tid = threadIdx.x, w = tid >> 6, lane = tid & 63;
    const int qt = blockIdx.x, h = blockIdx.y, b = blockIdx.z;
    const int q0 = qt * 64;
    const int win = *winp;
    const float scale = 0.125f;
    const int r16 = lane & 15, quad = lane >> 4;

    {
        int qr0 = tid >> 3, col0 = (tid & 7) * 8;
        async_copy16(&sQ[tid * 8], &q[(((size_t)b * 1024 + q0 + qr0) * 16 + h) * 64 + col0]);
        int c1 = tid + 256;
        int qr1 = c1 >> 3, col1 = (c1 & 7) * 8;
        async_copy16(&sQ[c1 * 8], &q[(((size_t)b * 1024 + q0 + qr1) * 16 + h) * 64 + col1]);
    }
    __syncthreads();
    bf16x8 aq0 = *(const bf16x8*)&sQ[(w * 16 + r16) * 64 + quad * 8];
    bf16x8 aq1 = *(const bf16x8*)&sQ[(w * 16 + r16) * 64 + 32 + quad * 8];

    float Lr[4];
    f32x4 zero = {0.f, 0.f, 0.f, 0.f};
    f32x4 accO[4];
    #pragma unroll
    for (int r = 0; r < 4; ++r) Lr[r] = 0.0f;
    #pragma unroll
    for (int nf = 0; nf < 4; ++nf) accO[nf] = zero;

    int lo = q0 - (win - 1); if (lo < 0) lo = 0;
    const int kt0 = lo >> 6;
    const bf16* vth = vt + ((size_t)b * 16 + h) * 64 * 1024;

    for (int kt = kt0; kt <= qt; ++kt) {
        __syncthreads();
        {
            int col0 = (tid & 7) * 8;
            async_copy16(&sK[tid * 8], &k[(((size_t)b * 1024 + kt * 64 + (tid >> 3)) * 16 + h) * 64 + col0]);
            int c1 = tid + 256;
            int col1 = (c1 & 7) * 8;
            async_copy16(&sK[c1 * 8], &k[(((size_t)b * 1024 + kt * 64 + (c1 >> 3)) * 16 + h) * 64 + col1]);
        }
        #pragma unroll
        for (int c = tid; c < 512; c += 256) {
            int hd = c >> 3, koff = (c & 7) * 8;
            *(u32x4*)&sVt[hd * 80 + koff] = *(const u32x4*)&vth[(size_t)hd * 1024 + kt * 64 + koff];
        }
        __syncthreads();

        f32x4 sf[4];
        #pragma unroll
        for (int nf = 0; nf < 4; ++nf) {
            bf16x8 bk0 = *(const bf16x8*)&sK[(nf * 16 + r16) * 64 + quad * 8];
            bf16x8 bk1 = *(const bf16x8*)&sK[(nf * 16 + r16) * 64 + 32 + quad * 8];
            f32x4 accS = zero;
            accS = __builtin_amdgcn_mfma_f32_16x16x32_bf16(aq0, bk0, accS, 0, 0, 0);
            accS = __builtin_amdgcn_mfma_f32_16x16x32_bf16(aq1, bk1, accS, 0, 0, 0);
            sf[nf] = accS;
        }

        #pragma unroll
        for (int r = 0; r < 4; ++r) {
            int i = q0 + w * 16 + quad * 4 + r;
            float ps = 0.0f;
            #pragma unroll
            for (int nf = 0; nf < 4; ++nf) {
                int j = kt * 64 + nf * 16 + r16;
                bool ok = (j <= i) && (i - j < win);
                float pv = ok ? __expf(sf[nf][r] * scale - 8.0f) : 0.0f;
                ps += pv;
                sP[(w * 16 + quad * 4 + r) * 64 + nf * 16 + r16] = (bf16)pv;
            }
            Lr[r] += ps;
        }
        __syncthreads();

        bf16x8 ap0 = *(const bf16x8*)&sP[(w * 16 + r16) * 64 + quad * 8];
        bf16x8 ap1 = *(const bf16x8*)&sP[(w * 16 + r16) * 64 + 32 + quad * 8];
        #pragma unroll
        for (int nf = 0; nf < 4; ++nf) {
            bf16x8 bv0 = *(const bf16x8*)&sVt[(nf * 16 + r16) * 80 + quad * 8];
            bf16x8 bv1 = *(const bf16x8*)&sVt[(nf * 16 + r16) * 80 + 32 + quad * 8];
            accO[nf] = __builtin_amdgcn_mfma_f32_16x16x32_bf16(ap0, bv0, accO[nf], 0, 0, 0);
            accO[nf] = __builtin_amdgcn_mfma_f32_16x16x32_bf16(ap1, bv1, accO[nf], 0, 0, 0);
        }
    }

    #pragma unroll
    for (int r = 0; r < 4; ++r) {
        float l = Lr[r];
        l += __shfl_xor(l, 1, 64);
        l += __shfl_xor(l, 2, 64);
        l += __shfl_xor(l, 4, 64);
        l += __shfl_xor(l, 8, 64);
        float inv = (l > 0.0f) ? 1.0f / l : 0.0f;
        int row = q0 + w * 16 + quad * 4 + r;
        #pragma unroll
        for (int nf = 0; nf < 4; ++nf) {
            float ov = fin0(accO[nf][r] * inv);
            o[(((size_t)b * 1024 + row) * 16 + h) * 64 + nf * 16 + r16] = (bf16)ov;
        }
    }
}

// ================= split-K=2 GEMM, 256x128 tile, 8 waves -> f32 partials =================
__global__ __launch_bounds__(512) void gemm_sk2(const bf16* __restrict__ A,
                                                const bf16* __restrict__ B,
                                                float* __restrict__ P,
                                                int K, int Kh) {
    __shared__ __align__(16) bf16 sA[2][256 * 32];
    __shared__ __align__(16) bf16 sB[2][128 * 32];
    const int tid = threadIdx.x;
    const int w = tid >> 6, lane = tid & 63;
    const int m0 = blockIdx.x * 256, n0 = blockIdx.y * 128;
    const int mwo = (w & 3) * 64, nwo = (w >> 2) * 64;
    const int r16 = lane & 15, quad = lane >> 4, kreg = quad * 8;
    const int kbase = blockIdx.z * Kh;
    const int N = 1024;

    const int ar0 = tid >> 2,        ak0 = (tid & 3) << 3;
    const int c1 = tid + 512;
    const int ar1 = c1 >> 2,         ak1 = (c1 & 3) << 3;
    const int br = tid >> 2,         bk = (tid & 3) << 3;

    f32x4 zero = {0.f, 0.f, 0.f, 0.f};
    f32x4 acc[4][4];
    #pragma unroll
    for (int i = 0; i < 4; ++i)
        #pragma unroll
        for (int j = 0; j < 4; ++j) acc[i][j] = zero;

    {
        async_copy16(&sA[0][tid * 8], &A[(size_t)(m0 + ar0) * K + kbase + ak0]);
        async_copy16(&sA[0][c1 * 8],  &A[(size_t)(m0 + ar1) * K + kbase + ak1]);
        async_copy16(&sB[0][tid * 8], &B[(size_t)(n0 + br) * K + kbase + bk]);
    }
    const int kIters = Kh >> 5;
    for (int kt = 0; kt < kIters; ++kt) {
        __syncthreads();
        const int cur = kt & 1, nxt = cur ^ 1;
        if (kt + 1 < kIters) {
            const int kb = kbase + ((kt + 1) << 5);
            async_copy16(&sA[nxt][tid * 8], &A[(size_t)(m0 + ar0) * K + kb + ak0]);
            async_copy16(&sA[nxt][c1 * 8],  &A[(size_t)(m0 + ar1) * K + kb + ak1]);
            async_copy16(&sB[nxt][tid * 8], &B[(size_t)(n0 + br) * K + kb + bk]);
        }
        bf16x8 af[4], bfr[4];
        #pragma unroll
        for (int i = 0; i < 4; ++i) {
            af[i]  = *(const bf16x8*)&sA[cur][(mwo + i * 16 + r16) * 32 + kreg];
            bfr[i] = *(const bf16x8*)&sB[cur][(nwo + i * 16 + r16) * 32 + kreg];
        }
        #pragma unroll
        for (int mi = 0; mi < 4; ++mi)
            #pragma unroll
            for (int ni = 0; ni < 4; ++ni)
                acc[mi][ni] = __builtin_amdgcn_mfma_f32_16x16x32_bf16(af[mi], bfr[ni], acc[mi][ni], 0, 0, 0);
    }

    float* Pz = P + (size_t)blockIdx.z * 4096 * 1024;
    #pragma unroll
    for (int mi = 0; mi < 4; ++mi)
        #pragma unroll
        for (int ni = 0; ni < 4; ++ni) {
            int col = n0 + nwo + ni * 16 + r16;
            #pragma unroll
            for (int r = 0; r < 4; ++r) {
                int row = m0 + mwo + mi * 16 + quad * 4 + r;
                Pz[(size_t)row * N + col] = acc[mi][ni][r];
            }
        }
}

// ================= resid+norm (dual f32 partials) =================
template <bool EMIT>
__global__ __launch_bounds__(512) void resid_norm(const float* __restrict__ xres,
                                                  const float* __restrict__ p0,
                                                  const float* __restrict__ p1,
                                                  const float* __restrict__ bias,
                                                  const float* __restrict__ wpost,
                                                  const float* __restrict__ wnext,
                                                  float* __restrict__ hout,
                                                  bf16* __restrict__ hnout) {
    __shared__ float sred[8];
    const int tid = threadIdx.x;
    const int grp = tid >> 8, t = tid & 255;
    const int w4 = (tid >> 6) & 3;
    for (int it = 0; it < 4; ++it) {
        int row = it * 1024 + blockIdx.x * 2 + grp;
        f32x4 a0 = ((const f32x4*)(p0 + (size_t)row * 1024))[t];
        f32x4 a1 = ((const f32x4*)(p1 + (size_t)row * 1024))[t];
        f32x4 bv = ((const f32x4*)bias)[t];
        f32x4 af;
        af[0] = clipf(a0[0] + a1[0] + bv[0]);
        af[1] = clipf(a0[1] + a1[1] + bv[1]);
        af[2] = clipf(a0[2] + a1[2] + bv[2]);
        af[3] = clipf(a0[3] + a1[3] + bv[3]);
        float ss = af[0]*af[0] + af[1]*af[1] + af[2]*af[2] + af[3]*af[3];
        #pragma unroll
        for (int off = 32; off >= 1; off >>= 1) ss += __shfl_xor(ss, off, 64);
        __syncthreads();
        if ((tid & 63) == 0) sred[grp * 4 + w4] = ss;
        __syncthreads();
        float tot = sred[grp*4+0] + sred[grp*4+1] + sred[grp*4+2] + sred[grp*4+3];
        float rms1 = sqrtf(fmaxf(tot * (1.0f / 1024.0f), EPS) + EPS);
        f32x4 xv = ((const f32x4*)(xres + (size_t)row * 1024))[t];
        f32x4 wp = ((const f32x4*)wpost)[t];
        f32x4 hv;
        hv[0] = xv[0] + fin0(af[0] / rms1 * wp[0]);
        hv[1] = xv[1] + fin0(af[1] / rms1 * wp[1]);
        hv[2] = xv[2] + fin0(af[2] / rms1 * wp[2]);
        hv[3] = xv[3] + fin0(af[3] / rms1 * wp[3]);
        ((f32x4*)(hout + (size_t)row * 1024))[t] = hv;
        if (EMIT) {
            f32x4 cv;
            cv[0] = clipf(hv[0]); cv[1] = clipf(hv[1]); cv[2] = clipf(hv[2]); cv[3] = clipf(hv[3]);
            float ss2 = cv[0]*cv[0] + cv[1]*cv[1] + cv[2]*cv[2] + cv[3]*cv[3];
            #pragma unroll
            for (int off = 32; off >= 1; off >>= 1) ss2 += __shfl_xor(ss2, off, 64);
            __syncthreads();
            if ((tid & 63) == 0) sred[grp * 4 + w4] = ss2;
            __syncthreads();
            float tot2 = sred[grp*4+0] + sred[grp*4+1] + sred[grp*4+2] + sred[grp*4+3];
            float rms2 = sqrtf(fmaxf(tot2 * (1.0f / 1024.0f), EPS) + EPS);
            f32x4 wn = ((const f32x4*)wnext)[t];
            bf16x4 o;
            o[0] = (bf16)fin0(cv[0] / rms2 * wn[0]);
            o[1] = (bf16)fin0(cv[1] / rms2 * wn[1]);
            o[2] = (bf16)fin0(cv[2] / rms2 * wn[2]);
            o[3] = (bf16)fin0(cv[3] / rms2 * wn[3]);
            *(bf16x4*)(hnout + (size_t)row * 1024 + t * 4) = o;
        }
    }
}

// ================= FFN1 v2: 256x256 tile, 2-barrier/tile pipelined schedule ================
// A: hn [4096][1024] bf16. Wf: interleaved W1/W3 [6656][1024] bf16 (16-row groups).
// grid 416 (16 m x 26 n, XCD-swizzled), block 512 (8 waves = 2M x 4N), LDS 128 KiB.
// Per K-tile t (BK=64):
//   BARRIER_A: protects stage A(t+1)->sA[nxt] vs tile(t-1) A reads (drained by prior
//              loop-end lgkmcnt(0)).
//   read B frags (8 ds) + A q0,q1 (8 ds); MFMA q0 (consumes ALL B frags);
//   lgkmcnt(0)+sched_barrier -> BARRIER_B: all waves' B reads retired before
//   stage B(t+2) overwrites sB[cur].  q1..q3 run unfenced (compiler pipelines A reads).
//   PRE-barrier counted vmcnt(4): outstanding = B(t+1)4 + A(t+1)4 + B(t+2)4 = 12;
//   retiring all but newest 4 makes A(t+1),B(t+1) globally visible at next BARRIER_A
//   (per-wave vmcnt + barrier = block-wide guarantee; this was r1's race).
template <int MB>
__device__ __forceinline__ void mquad(const bf16x8 (&a)[2][2], const bf16x8 (&breg)[4][2],
                                      f32x4 (&acc)[8][4]) {
    __builtin_amdgcn_s_setprio(1);
    #pragma unroll
    for (int n = 0; n < 4; ++n) {
        acc[MB][n]     = __builtin_amdgcn_mfma_f32_16x16x32_bf16(a[0][0], breg[n][0], acc[MB][n], 0, 0, 0);
        acc[MB][n]     = __builtin_amdgcn_mfma_f32_16x16x32_bf16(a[0][1], breg[n][1], acc[MB][n], 0, 0, 0);
        acc[MB + 1][n] = __builtin_amdgcn_mfma_f32_16x16x32_bf16(a[1][0], breg[n][0], acc[MB + 1][n], 0, 0, 0);
        acc[MB + 1][n] = __builtin_amdgcn_mfma_f32_16x16x32_bf16(a[1][1], breg[n][1], acc[MB + 1][n], 0, 0, 0);
    }
    __builtin_amdgcn_s_setprio(0);
}

__device__ __forceinline__ void aread(const bf16* Ah, int MB, int r16, int koff0, int koff1,
                                      bf16x8 (&a)[2][2]) {
    const bf16* p0 = &Ah[(MB * 16 + r16) * 64];
    const bf16* p1 = &Ah[((MB + 1) * 16 + r16) * 64];
    a[0][0] = *(const bf16x8*)&p0[koff0];
    a[0][1] = *(const bf16x8*)&p0[koff1];
    a[1][0] = *(const bf16x8*)&p1[koff0];
    a[1][1] = *(const bf16x8*)&p1[koff1];
}

__global__ __launch_bounds__(512, 2) void gemm_ffn1_8ph(const bf16* __restrict__ A,
                                                        const bf16* __restrict__ Wf,
                                                        const float* __restrict__ b1,
                                                        const float* __restrict__ b3,
                                                        bf16* __restrict__ G) {
    __shared__ __align__(16) bf16 sA[2][2][128 * 64];
    __shared__ __align__(16) bf16 sB[2][2][128 * 64];
    const int tid = threadIdx.x;
    const int w = tid >> 6, lane = tid & 63;
    const int wr = w >> 2, wc = w & 3;
    const int r16 = lane & 15, quad = lane >> 4;

    // XCD swizzle (416 % 8 == 0, bijective)
    const int flat = blockIdx.x;
    const int swb = (flat & 7) * 52 + (flat >> 3);
    const int bm = swb & 15, bn = swb >> 4;
    const int m0 = bm * 256;
    const int n0i = bn * 256;

    const int swz = r16 & 7;
    const int koff0 = ((quad ^ swz) << 3);
    const int koff1 = (((quad + 4) ^ swz) << 3);

    // staging: thread covers rows sr0 and sr0+64 of a 128-row half; source k pre-swizzled
    const int sr0 = tid >> 3, sr1 = sr0 + 64;
    const int sk0 = (((tid & 7) ^ (sr0 & 7)) << 3);

    const bf16* aSrc0 = A + (size_t)m0 * 1024;
    const bf16* aSrc1 = A + (size_t)(m0 + 128) * 1024;
    const bf16* bSrc0 = Wf + (size_t)n0i * 1024;
    const bf16* bSrc1 = Wf + (size_t)(n0i + 128) * 1024;

#define STAGE(dst, src, ktile) do {                                                        \
        async_copy16(&(dst)[tid * 8],         (src) + (size_t)sr0 * 1024 + (ktile) * 64 + sk0); \
        async_copy16(&(dst)[(tid + 512) * 8], (src) + (size_t)sr1 * 1024 + (ktile) * 64 + sk0); \
    } while (0)

    f32x4 acc[8][4];
    #pragma unroll
    for (int i = 0; i < 8; ++i)
        #pragma unroll
        for (int j = 0; j < 4; ++j) acc[i][j] = (f32x4){0.f, 0.f, 0.f, 0.f};

    // prologue: A(0)[4 loads], B(0)[4], B(1)[4]; retire A(0),B(0) -> vmcnt(4)
    STAGE(sA[0][0], aSrc0, 0); STAGE(sA[0][1], aSrc1, 0);
    STAGE(sB[0][0], bSrc0, 0); STAGE(sB[0][1], bSrc1, 0);
    STAGE(sB[1][0], bSrc0, 1); STAGE(sB[1][1], bSrc1, 1);
    asm volatile("s_waitcnt vmcnt(4)" ::: "memory");
    __builtin_amdgcn_sched_barrier(0);

    for (int t = 0; t < 16; ++t) {
        const int cur = t & 1, nxt = cur ^ 1;
        const bf16* Ah = &sA[cur][wr][0];
        const bf16* Bh = &sB[cur][wc >> 1][0];
        const int rbB = (wc & 1) << 6;

        __builtin_amdgcn_s_barrier();                       // BARRIER_A
        if (t + 1 < 16) { STAGE(sA[nxt][0], aSrc0, t + 1); STAGE(sA[nxt][1], aSrc1, t + 1); }

        bf16x8 breg[4][2];
        #pragma unroll
        for (int n = 0; n < 4; ++n) {
            const bf16* p = &Bh[(rbB + n * 16 + r16) * 64];
            breg[n][0] = *(const bf16x8*)&p[koff0];
            breg[n][1] = *(const bf16x8*)&p[koff1];
        }
        bf16x8 a0[2][2], a1[2][2];
        aread(Ah, 0, r16, koff0, koff1, a0);
        aread(Ah, 2, r16, koff0, koff1, a1);
        mquad<0>(a0, breg, acc);                            // consumes all 8 B frags

        asm volatile("s_waitcnt lgkmcnt(0)" ::: "memory");  // all B reads retired
        __builtin_amdgcn_sched_barrier(0);
        __builtin_amdgcn_s_barrier();                       // BARRIER_B
        if (t + 2 < 16) { STAGE(sB[cur][0], bSrc0, t + 2); STAGE(sB[cur][1], bSrc1, t + 2); }

        bf16x8 a2[2][2];
        aread(Ah, 4, r16, koff0, koff1, a2);
        mquad<2>(a1, breg, acc);
        bf16x8 a3[2][2];
        aread(Ah, 6, r16, koff0, koff1, a3);
        mquad<4>(a2, breg, acc);
        mquad<6>(a3, breg, acc);

        // pre-barrier waits: lgkm drains this tile's A reads (protects sA[nxt] overwrite
        // after next BARRIER_A); counted vmcnt keeps only B(t+2) in flight.
        if (t < 14)       asm volatile("s_waitcnt lgkmcnt(0) vmcnt(4)" ::: "memory");
        else if (t == 14) asm volatile("s_waitcnt lgkmcnt(0) vmcnt(0)" ::: "memory");
        else              asm volatile("s_waitcnt lgkmcnt(0)" ::: "memory");
        __builtin_amdgcn_sched_barrier(0);
    }
#undef STAGE

    // swiglu epilogue: frag n even = z1, n odd = z3 (16-row interleave of Wf);
    // pair p=(0,1),(2,3) -> output col (bn*8 + wc*2 + p)*16 + r16
    #pragma unroll
    for (int m = 0; m < 8; ++m) {
        #pragma unroll
        for (int p = 0; p < 2; ++p) {
            int col = (bn * 8 + wc * 2 + p) * 16 + r16;
            float bb1 = (col < 3280) ? b1[col] : 0.0f;
            float bb3 = (col < 3280) ? b3[col] : 0.0f;
            #pragma unroll
            for (int rr = 0; rr < 4; ++rr) {
                int row = m0 + wr * 128 + m * 16 + quad * 4 + rr;
                float z1 = acc[m][2 * p][rr] + bb1;
                float z3 = acc[m][2 * p + 1][rr] + bb3;
                float s = z1 / (1.0f + __expf(-z1));
                G[(size_t)row * 3328 + col] = (bf16)(s * z3);
            }
        }
    }
}

extern "C" void kernel_launch(void* const* d_in, const int* in_sizes, int n_in,
                              void* d_out, int out_size, void* d_ws, size_t ws_size,
                              hipStream_t stream) {
    const float* x       = (const float*)d_in[0];
    const float* wq_w    = (const float*)d_in[1];
    const float* wq_b    = (const float*)d_in[2];
    const float* wk_w    = (const float*)d_in[3];
    const float* wk_b    = (const float*)d_in[4];
    const float* wv_w    = (const float*)d_in[5];
    const float* wv_b    = (const float*)d_in[6];
    const float* wo_w    = (const float*)d_in[7];
    const float* wo_b    = (const float*)d_in[8];
    const float* q_norm_w= (const float*)d_in[9];
    const float* k_norm_w= (const float*)d_in[10];
    const float* seq_norm_w      = (const float*)d_in[11];
    const float* seq_post_norm_w = (const float*)d_in[12];
    const float* ffn_norm_w      = (const float*)d_in[13];
    const float* ffn_post_norm_w = (const float*)d_in[14];
    const float* w1_w    = (const float*)d_in[15];
    const float* w1_b    = (const float*)d_in[16];
    const float* w2_w    = (const float*)d_in[17];
    const float* w2_b    = (const float*)d_in[18];
    const float* w3_w    = (const float*)d_in[19];
    const float* w3_b    = (const float*)d_in[20];
    const int*   winp    = (const int*)d_in[21];
    float* out = (float*)d_out;

    const size_t SZ_W   = 2097152;    // 1024*1024*2
    const size_t SZ_WP  = 6815744;    // 3328*1024*2
    const size_t SZ_ACT = 8388608;    // 4096*1024*2
    const size_t SZ_H   = 16777216;   // 4096*1024*4
    const size_t SZ_P   = 33554432;   // 2*4096*1024*4 (split-K partials)

    char* p = (char*)d_ws;
    bf16* Wq  = (bf16*)p; p += SZ_W;
    bf16* Wk  = (bf16*)p; p += SZ_W;
    bf16* Wv  = (bf16*)p; p += SZ_W;
    bf16* Wo  = (bf16*)p; p += SZ_W;
    bf16* Wfp = (bf16*)p; p += 2 * SZ_WP;   // 6656x1024 interleaved W1/W3
    bf16* W2p = (bf16*)p; p += SZ_WP;
    float* h  = (float*)p; p += SZ_H;
    bf16* hn  = (bf16*)p; p += SZ_ACT;
    float* part = (float*)p; p += SZ_P;
    float* part1 = part + (size_t)4096 * 1024;
    char* regionA = p;  // aliased: attn-phase buffers, later g
    bf16* xn    = (bf16*)(regionA);
    bf16* qb    = (bf16*)(regionA + 1 * SZ_ACT);
    bf16* kb    = (bf16*)(regionA + 2 * SZ_ACT);
    bf16* vtb   = (bf16*)(regionA + 3 * SZ_ACT);
    bf16* attnb = (bf16*)(regionA + 4 * SZ_ACT);
    bf16* g     = (bf16*)(regionA);   // 27.3 MB; reuses xn..vtb after attention phase

    // 1) prep: all converts (W1/W3 interleaved) + rmsnorm(x)
    prep<<<dim3(15872), dim3(256), 0, stream>>>(wq_w, wk_w, wv_w, wo_w, Wq, Wk, Wv, Wo,
                                                w1_w, w3_w, Wfp, w2_w, W2p,
                                                x, seq_norm_w, xn);

    // 2) QKV projections; q,k head-normed; v transposed
    gemm_qkv<<<dim3(32, 8, 3), dim3(256), 0, stream>>>(xn, Wq, Wk, Wv, wq_b, wk_b, wv_b,
                                                       q_norm_w, k_norm_w, qb, kb, vtb);

    // 3) windowed causal attention (fixed-max softmax)
    attn_win<<<dim3(16, 16, 4), dim3(256), 0, stream>>>(qb, kb, vtb, winp, attnb);

    // 4) O-projection: 256x128 split-K=2 -> f32 partials (K=1024, Kh=512)
    gemm_sk2<<<dim3(16, 8, 2), dim3(512), 0, stream>>>(attnb, Wo, part, 1024, 512);

    // 5) h = x + rmsnorm(p0+p1+wo_b, seq_post); hn = rmsnorm(h, ffn_norm)
    resid_norm<true><<<dim3(512), dim3(512), 0, stream>>>(x, part, part1, wo_b,
                                                          seq_post_norm_w, ffn_norm_w, h, hn);

    // 6) fused FFN1 v2: 256x256, 2-barrier pipelined schedule, swiglu epilogue
    gemm_ffn1_8ph<<<dim3(416), dim3(512), 0, stream>>>(hn, Wfp, w1_b, w3_b, g);

    // 7) FFN2: 256x128 split-K=2 -> f32 partials (K=3328, Kh=1664, 52 iters)
    gemm_sk2<<<dim3(16, 8, 2), dim3(512), 0, stream>>>(g, W2p, part, 3328, 1664);

    // 8) out = h + rmsnorm(p0+p1+w2_b, ffn_post)
    resid_norm<false><<<dim3(512), dim3(512), 0, stream>>>(h, part, part1, w2_b,
                                                           ffn_post_norm_w, nullptr, out, nullptr);
}

// Round 3
// 374.312 us; speedup vs baseline: 1.0461x; 1.0345x over previous
//
#include <hip/hip_runtime.h>
#include <cmath>
#include <cstdint>

typedef __bf16 bf16;
typedef bf16 bf16x4 __attribute__((ext_vector_type(4)));
typedef bf16 bf16x8 __attribute__((ext_vector_type(8)));
typedef float f32x4 __attribute__((ext_vector_type(4)));
typedef unsigned int u32;
typedef u32 u32x4 __attribute__((ext_vector_type(4)));

#define EPS 1e-5f

__device__ __forceinline__ float clipf(float v) {
    return fminf(fmaxf(v, -10000.0f), 10000.0f);
}
__device__ __forceinline__ float fin0(float v) { return isfinite(v) ? v : 0.0f; }

__device__ __forceinline__ void async_copy16(void* lds, const void* g) {
    __builtin_amdgcn_global_load_lds((__attribute__((address_space(1))) void*)(void*)g,
                                     (__attribute__((address_space(3))) void*)lds,
                                     16, 0, 0);
}

// ================= prep: all weight converts + input rmsnorm, one dispatch =================
// flat grid 15872 blocks x 256 thr.  W1/W3 written INTERLEAVED (16-row groups) into Wf.
__global__ __launch_bounds__(256) void prep(const float* __restrict__ wq, const float* __restrict__ wk,
                                            const float* __restrict__ wv, const float* __restrict__ wo,
                                            bf16* __restrict__ Wq, bf16* __restrict__ Wk,
                                            bf16* __restrict__ Wv, bf16* __restrict__ Wo,
                                            const float* __restrict__ w1, const float* __restrict__ w3,
                                            bf16* __restrict__ Wf,
                                            const float* __restrict__ w2, bf16* __restrict__ W2p,
                                            const float* __restrict__ x, const float* __restrict__ snw,
                                            bf16* __restrict__ xn) {
    const int bid = blockIdx.x, t = threadIdx.x;
    if (bid < 4096) {
        int z = bid >> 10, r = bid & 1023;
        const float* in = (z == 0) ? wq : (z == 1) ? wk : (z == 2) ? wv : wo;
        bf16* out = (z == 0) ? Wq : (z == 1) ? Wk : (z == 2) ? Wv : Wo;
        f32x4 v = ((const f32x4*)(in + (size_t)r * 1024))[t];
        bf16x4 o = {(bf16)v[0], (bf16)v[1], (bf16)v[2], (bf16)v[3]};
        ((bf16x4*)(out + (size_t)r * 1024))[t] = o;
    } else if (bid < 10752) {
        int ri = bid - 4096;
        int lc = ((ri >> 5) << 4) + (ri & 15);
        const float* in = ((ri >> 4) & 1) ? w3 : w1;
        bf16x4 o = {(bf16)0.f, (bf16)0.f, (bf16)0.f, (bf16)0.f};
        if (lc < 3280) {
            f32x4 v = ((const f32x4*)(in + (size_t)lc * 1024))[t];
            o[0] = (bf16)v[0]; o[1] = (bf16)v[1]; o[2] = (bf16)v[2]; o[3] = (bf16)v[3];
        }
        ((bf16x4*)(Wf + (size_t)ri * 1024))[t] = o;
    } else if (bid < 11776) {
        int r = bid - 10752;
        for (int c4 = t * 4; c4 < 3328; c4 += 1024) {
            bf16x4 o = {(bf16)0.f, (bf16)0.f, (bf16)0.f, (bf16)0.f};
            if (c4 + 3 < 3280) {
                f32x4 v = *(const f32x4*)(w2 + (size_t)r * 3280 + c4);
                o[0] = (bf16)v[0]; o[1] = (bf16)v[1]; o[2] = (bf16)v[2]; o[3] = (bf16)v[3];
            } else {
                #pragma unroll
                for (int j = 0; j < 4; ++j)
                    if (c4 + j < 3280) o[j] = (bf16)w2[(size_t)r * 3280 + c4 + j];
            }
            *(bf16x4*)(W2p + (size_t)r * 3328 + c4) = o;
        }
    } else {
        __shared__ float sred[4];
        int row = bid - 11776;
        f32x4 xv = ((const f32x4*)(x + (size_t)row * 1024))[t];
        f32x4 cv;
        cv[0] = clipf(xv[0]); cv[1] = clipf(xv[1]); cv[2] = clipf(xv[2]); cv[3] = clipf(xv[3]);
        float ss = cv[0]*cv[0] + cv[1]*cv[1] + cv[2]*cv[2] + cv[3]*cv[3];
        #pragma unroll
        for (int off = 32; off >= 1; off >>= 1) ss += __shfl_xor(ss, off, 64);
        if ((t & 63) == 0) sred[t >> 6] = ss;
        __syncthreads();
        float tot = sred[0] + sred[1] + sred[2] + sred[3];
        float rms = sqrtf(fmaxf(tot * (1.0f / 1024.0f), EPS) + EPS);
        f32x4 wv_ = ((const f32x4*)snw)[t];
        bf16x4 o;
        o[0] = (bf16)fin0(cv[0] / rms * wv_[0]);
        o[1] = (bf16)fin0(cv[1] / rms * wv_[1]);
        o[2] = (bf16)fin0(cv[2] / rms * wv_[2]);
        o[3] = (bf16)fin0(cv[3] / rms * wv_[3]);
        *(bf16x4*)(xn + (size_t)row * 1024 + t * 4) = o;
    }
}

// ================= QKV GEMM (dbuf), fused head-rmsnorm (q,k), vT epilogue =================
// grid (32, 8, 3), block 256.
__global__ __launch_bounds__(256) void gemm_qkv(const bf16* __restrict__ A,
                                                const bf16* __restrict__ B0,
                                                const bf16* __restrict__ B1,
                                                const bf16* __restrict__ B2,
                                                const float* __restrict__ g0,
                                                const float* __restrict__ g1,
                                                const float* __restrict__ g2,
                                                const float* __restrict__ qnw,
                                                const float* __restrict__ knw,
                                                bf16* __restrict__ C0,
                                                bf16* __restrict__ C1,
                                                bf16* __restrict__ VT) {
    const int z = blockIdx.z;
    const bf16* B = (z == 0) ? B0 : (z == 1) ? B1 : B2;
    const float* bias = (z == 0) ? g0 : (z == 1) ? g1 : g2;
    const float* hw = (z == 0) ? qnw : knw;

    __shared__ __align__(16) bf16 sA[2][128 * 32];
    __shared__ __align__(16) bf16 sB[2][128 * 32];
    const int tid = threadIdx.x;
    const int w = tid >> 6, lane = tid & 63;
    const int m0 = blockIdx.x * 128;
    const int n0 = blockIdx.y * 128;
    const int mwo = (w >> 1) * 64, nwo = (w & 1) * 64;
    const int r16 = lane & 15, quad = lane >> 4;
    const int kreg = quad * 8;
    const int K = 1024, N = 1024;

    f32x4 zero = {0.f, 0.f, 0.f, 0.f};
    f32x4 acc[4][4];
    #pragma unroll
    for (int i = 0; i < 4; ++i)
        #pragma unroll
        for (int j = 0; j < 4; ++j) acc[i][j] = zero;

    const int c0 = tid, c1 = tid + 256;
    const int am0 = c0 >> 2, ak0 = (c0 & 3) << 3;
    const int am1 = c1 >> 2, ak1 = (c1 & 3) << 3;

    {
        async_copy16(&sA[0][c0 * 8], &A[(size_t)(m0 + am0) * K + ak0]);
        async_copy16(&sA[0][c1 * 8], &A[(size_t)(m0 + am1) * K + ak1]);
        async_copy16(&sB[0][c0 * 8], &B[(size_t)(n0 + am0) * K + ak0]);
        async_copy16(&sB[0][c1 * 8], &B[(size_t)(n0 + am1) * K + ak1]);
    }
    for (int kt = 0; kt < 32; ++kt) {
        __syncthreads();
        const int cur = kt & 1, nxt = cur ^ 1;
        if (kt + 1 < 32) {
            const int kb = (kt + 1) << 5;
            async_copy16(&sA[nxt][c0 * 8], &A[(size_t)(m0 + am0) * K + kb + ak0]);
            async_copy16(&sA[nxt][c1 * 8], &A[(size_t)(m0 + am1) * K + kb + ak1]);
            async_copy16(&sB[nxt][c0 * 8], &B[(size_t)(n0 + am0) * K + kb + ak0]);
            async_copy16(&sB[nxt][c1 * 8], &B[(size_t)(n0 + am1) * K + kb + ak1]);
        }
        bf16x8 af[4], bfr[4];
        #pragma unroll
        for (int i = 0; i < 4; ++i) {
            af[i]  = *(const bf16x8*)&sA[cur][(mwo + i * 16 + r16) * 32 + kreg];
            bfr[i] = *(const bf16x8*)&sB[cur][(nwo + i * 16 + r16) * 32 + kreg];
        }
        #pragma unroll
        for (int mi = 0; mi < 4; ++mi)
            #pragma unroll
            for (int ni = 0; ni < 4; ++ni)
                acc[mi][ni] = __builtin_amdgcn_mfma_f32_16x16x32_bf16(af[mi], bfr[ni], acc[mi][ni], 0, 0, 0);
    }

    float bv[4];
    #pragma unroll
    for (int ni = 0; ni < 4; ++ni) bv[ni] = bias[n0 + nwo + ni * 16 + r16];

    if (z < 2) {
        bf16* C = (z == 0) ? C0 : C1;
        float nwv[4];
        #pragma unroll
        for (int ni = 0; ni < 4; ++ni) nwv[ni] = hw[ni * 16 + r16];
        #pragma unroll
        for (int mi = 0; mi < 4; ++mi) {
            #pragma unroll
            for (int r = 0; r < 4; ++r) {
                float v[4], ss = 0.0f;
                #pragma unroll
                for (int ni = 0; ni < 4; ++ni) {
                    v[ni] = clipf(acc[mi][ni][r] + bv[ni]);
                    ss += v[ni] * v[ni];
                }
                ss += __shfl_xor(ss, 1, 64);
                ss += __shfl_xor(ss, 2, 64);
                ss += __shfl_xor(ss, 4, 64);
                ss += __shfl_xor(ss, 8, 64);
                float rms = sqrtf(fmaxf(ss * (1.0f / 64.0f), EPS) + EPS);
                int row = m0 + mwo + mi * 16 + quad * 4 + r;
                #pragma unroll
                for (int ni = 0; ni < 4; ++ni) {
                    int col = n0 + nwo + ni * 16 + r16;
                    C[(size_t)row * N + col] = (bf16)fin0(v[ni] / rms * nwv[ni]);
                }
            }
        }
    } else {
        const int b_ = m0 >> 10;
        const int tokbase = (m0 & 1023) + mwo;
        #pragma unroll
        for (int ni = 0; ni < 4; ++ni) {
            int col = n0 + nwo + ni * 16 + r16;
            int h_ = col >> 6, hd = col & 63;
            bf16* dst = VT + (((size_t)b_ * 16 + h_) * 64 + hd) * 1024;
            #pragma unroll
            for (int mi = 0; mi < 4; ++mi) {
                bf16x4 pack;
                #pragma unroll
                for (int r = 0; r < 4; ++r) pack[r] = (bf16)(acc[mi][ni][r] + bv[ni]);
                *(bf16x4*)&dst[tokbase + mi * 16 + quad * 4] = pack;
            }
        }
    }
}

// ================= windowed causal flash attention, FIXED-MAX softmax (r9) =================
// grid: (L/64, H, B), block 256. q/k: (B,L,H,64); vt: (B,H,64,L).
__global__ __launch_bounds__(256) void attn_win(const bf16* __restrict__ q,
                                                const bf16* __restrict__ k,
                                                const bf16* __restrict__ vt,
                                                const int* __restrict__ winp,
                                                bf16* __restrict__ o) {
    __shared__ __align__(16) bf16 sQ[64 * 64];
    __shared__ __align__(16) bf16 sK[64 * 64];
    __shared__ __align__(16) bf16 sVt[64 * 80];
    __shared__ __align__(16) bf16 sP[64 * 64];
    const int tid = threadIdx.x, w = tid >> 6, lane = tid & 63;
    const int qt = blockIdx.x, h = blockIdx.y, b = blockIdx.z;
    const int q0 = qt * 64;
    const int win = *winp;
    const float scale = 0.125f;
    const int r16 = lane & 15, quad = lane >> 4;

    {
        int qr0 = tid >> 3, col0 = (tid & 7) * 8;
        async_copy16(&sQ[tid * 8], &q[(((size_t)b * 1024 + q0 + qr0) * 16 + h) * 64 + col0]);
        int c1 = tid + 256;
        int qr1 = c1 >> 3, col1 = (c1 & 7) * 8;
        async_copy16(&sQ[c1 * 8], &q[(((size_t)b * 1024 + q0 + qr1) * 16 + h) * 64 + col1]);
    }
    __syncthreads();
    bf16x8 aq0 = *(const bf16x8*)&sQ[(w * 16 + r16) * 64 + quad * 8];
    bf16x8 aq1 = *(const bf16x8*)&sQ[(w * 16 + r16) * 64 + 32 + quad * 8];

    float Lr[4];
    f32x4 zero = {0.f, 0.f, 0.f, 0.f};
    f32x4 accO[4];
    #pragma unroll
    for (int r = 0; r < 4; ++r) Lr[r] = 0.0f;
    #pragma unroll
    for (int nf = 0; nf < 4; ++nf) accO[nf] = zero;

    int lo = q0 - (win - 1); if (lo < 0) lo = 0;
    const int kt0 = lo >> 6;
    const bf16* vth = vt + ((size_t)b * 16 + h) * 64 * 1024;

    for (int kt = kt0; kt <= qt; ++kt) {
        __syncthreads();
        {
            int col0 = (tid & 7) * 8;
            async_copy16(&sK[tid * 8], &k[(((size_t)b * 1024 + kt * 64 + (tid >> 3)) * 16 + h) * 64 + col0]);
            int c1 = tid + 256;
            int col1 = (c1 & 7) * 8;
            async_copy16(&sK[c1 * 8], &k[(((size_t)b * 1024 + kt * 64 + (c1 >> 3)) * 16 + h) * 64 + col1]);
        }
        #pragma unroll
        for (int c = tid; c < 512; c += 256) {
            int hd = c >> 3, koff = (c & 7) * 8;
            *(u32x4*)&sVt[hd * 80 + koff] = *(const u32x4*)&vth[(size_t)hd * 1024 + kt * 64 + koff];
        }
        __syncthreads();

        f32x4 sf[4];
        #pragma unroll
        for (int nf = 0; nf < 4; ++nf) {
            bf16x8 bk0 = *(const bf16x8*)&sK[(nf * 16 + r16) * 64 + quad * 8];
            bf16x8 bk1 = *(const bf16x8*)&sK[(nf * 16 + r16) * 64 + 32 + quad * 8];
            f32x4 accS = zero;
            accS = __builtin_amdgcn_mfma_f32_16x16x32_bf16(aq0, bk0, accS, 0, 0, 0);
            accS = __builtin_amdgcn_mfma_f32_16x16x32_bf16(aq1, bk1, accS, 0, 0, 0);
            sf[nf] = accS;
        }

        #pragma unroll
        for (int r = 0; r < 4; ++r) {
            int i = q0 + w * 16 + quad * 4 + r;
            float ps = 0.0f;
            #pragma unroll
            for (int nf = 0; nf < 4; ++nf) {
                int j = kt * 64 + nf * 16 + r16;
                bool ok = (j <= i) && (i - j < win);
                float pv = ok ? __expf(sf[nf][r] * scale - 8.0f) : 0.0f;
                ps += pv;
                sP[(w * 16 + quad * 4 + r) * 64 + nf * 16 + r16] = (bf16)pv;
            }
            Lr[r] += ps;
        }
        __syncthreads();

        bf16x8 ap0 = *(const bf16x8*)&sP[(w * 16 + r16) * 64 + quad * 8];
        bf16x8 ap1 = *(const bf16x8*)&sP[(w * 16 + r16) * 64 + 32 + quad * 8];
        #pragma unroll
        for (int nf = 0; nf < 4; ++nf) {
            bf16x8 bv0 = *(const bf16x8*)&sVt[(nf * 16 + r16) * 80 + quad * 8];
            bf16x8 bv1 = *(const bf16x8*)&sVt[(nf * 16 + r16) * 80 + 32 + quad * 8];
            accO[nf] = __builtin_amdgcn_mfma_f32_16x16x32_bf16(ap0, bv0, accO[nf], 0, 0, 0);
            accO[nf] = __builtin_amdgcn_mfma_f32_16x16x32_bf16(ap1, bv1, accO[nf], 0, 0, 0);
        }
    }

    #pragma unroll
    for (int r = 0; r < 4; ++r) {
        float l = Lr[r];
        l += __shfl_xor(l, 1, 64);
        l += __shfl_xor(l, 2, 64);
        l += __shfl_xor(l, 4, 64);
        l += __shfl_xor(l, 8, 64);
        float inv = (l > 0.0f) ? 1.0f / l : 0.0f;
        int row = q0 + w * 16 + quad * 4 + r;
        #pragma unroll
        for (int nf = 0; nf < 4; ++nf) {
            float ov = fin0(accO[nf][r] * inv);
            o[(((size_t)b * 1024 + row) * 16 + h) * 64 + nf * 16 + r16] = (bf16)ov;
        }
    }
}

// ================= split-K=2 GEMM, 256x128 tile, 8 waves -> f32 partials =================
__global__ __launch_bounds__(512) void gemm_sk2(const bf16* __restrict__ A,
                                                const bf16* __restrict__ B,
                                                float* __restrict__ P,
                                                int K, int Kh) {
    __shared__ __align__(16) bf16 sA[2][256 * 32];
    __shared__ __align__(16) bf16 sB[2][128 * 32];
    const int tid = threadIdx.x;
    const int w = tid >> 6, lane = tid & 63;
    const int m0 = blockIdx.x * 256, n0 = blockIdx.y * 128;
    const int mwo = (w & 3) * 64, nwo = (w >> 2) * 64;
    const int r16 = lane & 15, quad = lane >> 4, kreg = quad * 8;
    const int kbase = blockIdx.z * Kh;
    const int N = 1024;

    const int ar0 = tid >> 2,        ak0 = (tid & 3) << 3;
    const int c1 = tid + 512;
    const int ar1 = c1 >> 2,         ak1 = (c1 & 3) << 3;
    const int br = tid >> 2,         bk = (tid & 3) << 3;

    f32x4 zero = {0.f, 0.f, 0.f, 0.f};
    f32x4 acc[4][4];
    #pragma unroll
    for (int i = 0; i < 4; ++i)
        #pragma unroll
        for (int j = 0; j < 4; ++j) acc[i][j] = zero;

    {
        async_copy16(&sA[0][tid * 8], &A[(size_t)(m0 + ar0) * K + kbase + ak0]);
        async_copy16(&sA[0][c1 * 8],  &A[(size_t)(m0 + ar1) * K + kbase + ak1]);
        async_copy16(&sB[0][tid * 8], &B[(size_t)(n0 + br) * K + kbase + bk]);
    }
    const int kIters = Kh >> 5;
    for (int kt = 0; kt < kIters; ++kt) {
        __syncthreads();
        const int cur = kt & 1, nxt = cur ^ 1;
        if (kt + 1 < kIters) {
            const int kb = kbase + ((kt + 1) << 5);
            async_copy16(&sA[nxt][tid * 8], &A[(size_t)(m0 + ar0) * K + kb + ak0]);
            async_copy16(&sA[nxt][c1 * 8],  &A[(size_t)(m0 + ar1) * K + kb + ak1]);
            async_copy16(&sB[nxt][tid * 8], &B[(size_t)(n0 + br) * K + kb + bk]);
        }
        bf16x8 af[4], bfr[4];
        #pragma unroll
        for (int i = 0; i < 4; ++i) {
            af[i]  = *(const bf16x8*)&sA[cur][(mwo + i * 16 + r16) * 32 + kreg];
            bfr[i] = *(const bf16x8*)&sB[cur][(nwo + i * 16 + r16) * 32 + kreg];
        }
        #pragma unroll
        for (int mi = 0; mi < 4; ++mi)
            #pragma unroll
            for (int ni = 0; ni < 4; ++ni)
                acc[mi][ni] = __builtin_amdgcn_mfma_f32_16x16x32_bf16(af[mi], bfr[ni], acc[mi][ni], 0, 0, 0);
    }

    float* Pz = P + (size_t)blockIdx.z * 4096 * 1024;
    #pragma unroll
    for (int mi = 0; mi < 4; ++mi)
        #pragma unroll
        for (int ni = 0; ni < 4; ++ni) {
            int col = n0 + nwo + ni * 16 + r16;
            #pragma unroll
            for (int r = 0; r < 4; ++r) {
                int row = m0 + mwo + mi * 16 + quad * 4 + r;
                Pz[(size_t)row * N + col] = acc[mi][ni][r];
            }
        }
}

// ================= resid+norm (dual f32 partials) =================
template <bool EMIT>
__global__ __launch_bounds__(512) void resid_norm(const float* __restrict__ xres,
                                                  const float* __restrict__ p0,
                                                  const float* __restrict__ p1,
                                                  const float* __restrict__ bias,
                                                  const float* __restrict__ wpost,
                                                  const float* __restrict__ wnext,
                                                  float* __restrict__ hout,
                                                  bf16* __restrict__ hnout) {
    __shared__ float sred[8];
    const int tid = threadIdx.x;
    const int grp = tid >> 8, t = tid & 255;
    const int w4 = (tid >> 6) & 3;
    for (int it = 0; it < 4; ++it) {
        int row = it * 1024 + blockIdx.x * 2 + grp;
        f32x4 a0 = ((const f32x4*)(p0 + (size_t)row * 1024))[t];
        f32x4 a1 = ((const f32x4*)(p1 + (size_t)row * 1024))[t];
        f32x4 bv = ((const f32x4*)bias)[t];
        f32x4 af;
        af[0] = clipf(a0[0] + a1[0] + bv[0]);
        af[1] = clipf(a0[1] + a1[1] + bv[1]);
        af[2] = clipf(a0[2] + a1[2] + bv[2]);
        af[3] = clipf(a0[3] + a1[3] + bv[3]);
        float ss = af[0]*af[0] + af[1]*af[1] + af[2]*af[2] + af[3]*af[3];
        #pragma unroll
        for (int off = 32; off >= 1; off >>= 1) ss += __shfl_xor(ss, off, 64);
        __syncthreads();
        if ((tid & 63) == 0) sred[grp * 4 + w4] = ss;
        __syncthreads();
        float tot = sred[grp*4+0] + sred[grp*4+1] + sred[grp*4+2] + sred[grp*4+3];
        float rms1 = sqrtf(fmaxf(tot * (1.0f / 1024.0f), EPS) + EPS);
        f32x4 xv = ((const f32x4*)(xres + (size_t)row * 1024))[t];
        f32x4 wp = ((const f32x4*)wpost)[t];
        f32x4 hv;
        hv[0] = xv[0] + fin0(af[0] / rms1 * wp[0]);
        hv[1] = xv[1] + fin0(af[1] / rms1 * wp[1]);
        hv[2] = xv[2] + fin0(af[2] / rms1 * wp[2]);
        hv[3] = xv[3] + fin0(af[3] / rms1 * wp[3]);
        ((f32x4*)(hout + (size_t)row * 1024))[t] = hv;
        if (EMIT) {
            f32x4 cv;
            cv[0] = clipf(hv[0]); cv[1] = clipf(hv[1]); cv[2] = clipf(hv[2]); cv[3] = clipf(hv[3]);
            float ss2 = cv[0]*cv[0] + cv[1]*cv[1] + cv[2]*cv[2] + cv[3]*cv[3];
            #pragma unroll
            for (int off = 32; off >= 1; off >>= 1) ss2 += __shfl_xor(ss2, off, 64);
            __syncthreads();
            if ((tid & 63) == 0) sred[grp * 4 + w4] = ss2;
            __syncthreads();
            float tot2 = sred[grp*4+0] + sred[grp*4+1] + sred[grp*4+2] + sred[grp*4+3];
            float rms2 = sqrtf(fmaxf(tot2 * (1.0f / 1024.0f), EPS) + EPS);
            f32x4 wn = ((const f32x4*)wnext)[t];
            bf16x4 o;
            o[0] = (bf16)fin0(cv[0] / rms2 * wn[0]);
            o[1] = (bf16)fin0(cv[1] / rms2 * wn[1]);
            o[2] = (bf16)fin0(cv[2] / rms2 * wn[2]);
            o[3] = (bf16)fin0(cv[3] / rms2 * wn[3]);
            *(bf16x4*)(hnout + (size_t)row * 1024 + t * 4) = o;
        }
    }
}

// ================= FFN1 v3: 256x256 tile, ROTATED 4-phase schedule (m201 port) =============
// A: hn [4096][1024] bf16. Wf: interleaved W1/W3 [6656][1024] bf16 (16-row groups).
// grid 416 (16 m x 26 n, XCD-swizzled), block 512 (8 waves = 2M x 4N), LDS 128 KiB.
// Rotation: each phase's ds_reads are consumed by the NEXT phase's MFMA; the reads'
// latency hides under the CURRENT phase's MFMA pipe drain (issue << execute).
// Per tile t:  [Qk = mquad<2k>, 16 MFMA each]
//  ph0: lgkm0 (retire a3(t-1)); vmcnt(4) counted; barrier;
//       stage A(t+1)h0; MFMA Q3(t-1); read breg(t)[8]+a0(t)[4]; barrier
//  ph1: stage A(t+1)h1; read a1; MFMA Q0(t); barrier
//  ph2: stage B(t+2)h0 (sB[cur] free: breg retired @ph1, published by ph1 barrier);
//       read a2; MFMA Q1(t); barrier
//  ph3: stage B(t+2)h1; read a3 -> loop-carried; MFMA Q2(t); barrier
// vm ledger @ph0(t): outstanding = B(t)h0,h1, A(t)h0,h1, B(t+1)h0,h1 (12 loads);
// vmcnt(4) retires through A(t)h1 -> A(t),B(t) published by the following barrier.
// Never drains to 0 until t=15.
template <int MB>
__device__ __forceinline__ void mquad(const bf16x8 (&a)[2][2], const bf16x8 (&breg)[4][2],
                                      f32x4 (&acc)[8][4]) {
    __builtin_amdgcn_s_setprio(1);
    #pragma unroll
    for (int n = 0; n < 4; ++n) {
        acc[MB][n]     = __builtin_amdgcn_mfma_f32_16x16x32_bf16(a[0][0], breg[n][0], acc[MB][n], 0, 0, 0);
        acc[MB][n]     = __builtin_amdgcn_mfma_f32_16x16x32_bf16(a[0][1], breg[n][1], acc[MB][n], 0, 0, 0);
        acc[MB + 1][n] = __builtin_amdgcn_mfma_f32_16x16x32_bf16(a[1][0], breg[n][0], acc[MB + 1][n], 0, 0, 0);
        acc[MB + 1][n] = __builtin_amdgcn_mfma_f32_16x16x32_bf16(a[1][1], breg[n][1], acc[MB + 1][n], 0, 0, 0);
    }
    __builtin_amdgcn_s_setprio(0);
}

__device__ __forceinline__ void aread(const bf16* Ah, int MB, int r16, int koff0, int koff1,
                                      bf16x8 (&a)[2][2]) {
    const bf16* p0 = &Ah[(MB * 16 + r16) * 64];
    const bf16* p1 = &Ah[((MB + 1) * 16 + r16) * 64];
    a[0][0] = *(const bf16x8*)&p0[koff0];
    a[0][1] = *(const bf16x8*)&p0[koff1];
    a[1][0] = *(const bf16x8*)&p1[koff0];
    a[1][1] = *(const bf16x8*)&p1[koff1];
}

__global__ __launch_bounds__(512, 2) void gemm_ffn1_8ph(const bf16* __restrict__ A,
                                                        const bf16* __restrict__ Wf,
                                                        const float* __restrict__ b1,
                                                        const float* __restrict__ b3,
                                                        bf16* __restrict__ G) {
    __shared__ __align__(16) bf16 sA[2][2][128 * 64];
    __shared__ __align__(16) bf16 sB[2][2][128 * 64];
    const int tid = threadIdx.x;
    const int w = tid >> 6, lane = tid & 63;
    const int wr = w >> 2, wc = w & 3;
    const int r16 = lane & 15, quad = lane >> 4;

    // XCD swizzle (416 % 8 == 0, bijective)
    const int flat = blockIdx.x;
    const int swb = (flat & 7) * 52 + (flat >> 3);
    const int bm = swb & 15, bn = swb >> 4;
    const int m0 = bm * 256;
    const int n0i = bn * 256;

    const int swz = r16 & 7;
    const int koff0 = ((quad ^ swz) << 3);
    const int koff1 = (((quad + 4) ^ swz) << 3);

    // staging: thread covers rows sr0 and sr0+64 of a 128-row half; source k pre-swizzled
    const int sr0 = tid >> 3, sr1 = sr0 + 64;
    const int sk0 = (((tid & 7) ^ (sr0 & 7)) << 3);

    const bf16* aSrc0 = A + (size_t)m0 * 1024;
    const bf16* aSrc1 = A + (size_t)(m0 + 128) * 1024;
    const bf16* bSrc0 = Wf + (size_t)n0i * 1024;
    const bf16* bSrc1 = Wf + (size_t)(n0i + 128) * 1024;

#define STAGE(dst, src, ktile) do {                                                        \
        async_copy16(&(dst)[tid * 8],         (src) + (size_t)sr0 * 1024 + (ktile) * 64 + sk0); \
        async_copy16(&(dst)[(tid + 512) * 8], (src) + (size_t)sr1 * 1024 + (ktile) * 64 + sk0); \
    } while (0)

    f32x4 acc[8][4];
    #pragma unroll
    for (int i = 0; i < 8; ++i)
        #pragma unroll
        for (int j = 0; j < 4; ++j) acc[i][j] = (f32x4){0.f, 0.f, 0.f, 0.f};

    // prologue, issue order = ledger order: B(0)h0,h1, A(0)h0,h1, B(1)h0,h1
    STAGE(sB[0][0], bSrc0, 0); STAGE(sB[0][1], bSrc1, 0);
    STAGE(sA[0][0], aSrc0, 0); STAGE(sA[0][1], aSrc1, 0);
    STAGE(sB[1][0], bSrc0, 1); STAGE(sB[1][1], bSrc1, 1);

    bf16x8 br[4][2];   // loop-carried B fragments (tile t)
    bf16x8 ah[2][2];   // loop-carried a3 fragments (tile t)

    for (int t = 0; t < 16; ++t) {
        const int cur = t & 1, nxt = cur ^ 1;
        const bf16* Ah = &sA[cur][wr][0];
        const bf16* Bh = &sB[cur][wc >> 1][0];
        const int rbB = (wc & 1) << 6;

        // ---- ph0 ----
        asm volatile("s_waitcnt lgkmcnt(0)" ::: "memory");   // retire a3(t-1) before A(t+1) stage
        if (t < 15) asm volatile("s_waitcnt vmcnt(4)" ::: "memory");
        else        asm volatile("s_waitcnt vmcnt(0)" ::: "memory");
        __builtin_amdgcn_sched_barrier(0);
        __builtin_amdgcn_s_barrier();                        // publish A(t),B(t); a3-retire block-wide
        if (t + 1 < 16) STAGE(sA[nxt][0], aSrc0, t + 1);
        if (t) mquad<6>(ah, br, acc);                        // Q3(t-1); reads below hide under drain
        __builtin_amdgcn_sched_barrier(0);                   // br dead -> RA may reuse for new reads
        #pragma unroll
        for (int n = 0; n < 4; ++n) {
            const bf16* p = &Bh[(rbB + n * 16 + r16) * 64];
            br[n][0] = *(const bf16x8*)&p[koff0];
            br[n][1] = *(const bf16x8*)&p[koff1];
        }
        bf16x8 a0[2][2];
        aread(Ah, 0, r16, koff0, koff1, a0);
        __builtin_amdgcn_sched_barrier(0);
        __builtin_amdgcn_s_barrier();

        // ---- ph1 ----
        if (t + 1 < 16) STAGE(sA[nxt][1], aSrc1, t + 1);
        bf16x8 a1[2][2];
        aread(Ah, 2, r16, koff0, koff1, a1);
        mquad<0>(a0, br, acc);                               // compiler waits br,a0 precisely
        __builtin_amdgcn_sched_barrier(0);
        __builtin_amdgcn_s_barrier();

        // ---- ph2 ----
        if (t + 2 < 16) STAGE(sB[cur][0], bSrc0, t + 2);     // breg retired @ph1, published
        bf16x8 a2[2][2];
        aread(Ah, 4, r16, koff0, koff1, a2);
        mquad<2>(a1, br, acc);
        __builtin_amdgcn_sched_barrier(0);
        __builtin_amdgcn_s_barrier();

        // ---- ph3 ----
        if (t + 2 < 16) STAGE(sB[cur][1], bSrc1, t + 2);
        aread(Ah, 6, r16, koff0, koff1, ah);                 // a3 -> loop-carried
        mquad<4>(a2, br, acc);
        __builtin_amdgcn_sched_barrier(0);
        __builtin_amdgcn_s_barrier();
    }
#undef STAGE
    // epilogue: Q3(15)
    asm volatile("s_waitcnt lgkmcnt(0)" ::: "memory");
    __builtin_amdgcn_sched_barrier(0);
    mquad<6>(ah, br, acc);

    // swiglu epilogue: frag n even = z1, n odd = z3 (16-row interleave of Wf);
    // pair p=(0,1),(2,3) -> output col (bn*8 + wc*2 + p)*16 + r16
    #pragma unroll
    for (int m = 0; m < 8; ++m) {
        #pragma unroll
        for (int p = 0; p < 2; ++p) {
            int col = (bn * 8 + wc * 2 + p) * 16 + r16;
            float bb1 = (col < 3280) ? b1[col] : 0.0f;
            float bb3 = (col < 3280) ? b3[col] : 0.0f;
            #pragma unroll
            for (int rr = 0; rr < 4; ++rr) {
                int row = m0 + wr * 128 + m * 16 + quad * 4 + rr;
                float z1 = acc[m][2 * p][rr] + bb1;
                float z3 = acc[m][2 * p + 1][rr] + bb3;
                float s = z1 / (1.0f + __expf(-z1));
                G[(size_t)row * 3328 + col] = (bf16)(s * z3);
            }
        }
    }
}

extern "C" void kernel_launch(void* const* d_in, const int* in_sizes, int n_in,
                              void* d_out, int out_size, void* d_ws, size_t ws_size,
                              hipStream_t stream) {
    const float* x       = (const float*)d_in[0];
    const float* wq_w    = (const float*)d_in[1];
    const float* wq_b    = (const float*)d_in[2];
    const float* wk_w    = (const float*)d_in[3];
    const float* wk_b    = (const float*)d_in[4];
    const float* wv_w    = (const float*)d_in[5];
    const float* wv_b    = (const float*)d_in[6];
    const float* wo_w    = (const float*)d_in[7];
    const float* wo_b    = (const float*)d_in[8];
    const float* q_norm_w= (const float*)d_in[9];
    const float* k_norm_w= (const float*)d_in[10];
    const float* seq_norm_w      = (const float*)d_in[11];
    const float* seq_post_norm_w = (const float*)d_in[12];
    const float* ffn_norm_w      = (const float*)d_in[13];
    const float* ffn_post_norm_w = (const float*)d_in[14];
    const float* w1_w    = (const float*)d_in[15];
    const float* w1_b    = (const float*)d_in[16];
    const float* w2_w    = (const float*)d_in[17];
    const float* w2_b    = (const float*)d_in[18];
    const float* w3_w    = (const float*)d_in[19];
    const float* w3_b    = (const float*)d_in[20];
    const int*   winp    = (const int*)d_in[21];
    float* out = (float*)d_out;

    const size_t SZ_W   = 2097152;    // 1024*1024*2
    const size_t SZ_WP  = 6815744;    // 3328*1024*2
    const size_t SZ_ACT = 8388608;    // 4096*1024*2
    const size_t SZ_H   = 16777216;   // 4096*1024*4
    const size_t SZ_P   = 33554432;   // 2*4096*1024*4 (split-K partials)

    char* p = (char*)d_ws;
    bf16* Wq  = (bf16*)p; p += SZ_W;
    bf16* Wk  = (bf16*)p; p += SZ_W;
    bf16* Wv  = (bf16*)p; p += SZ_W;
    bf16* Wo  = (bf16*)p; p += SZ_W;
    bf16* Wfp = (bf16*)p; p += 2 * SZ_WP;   // 6656x1024 interleaved W1/W3
    bf16* W2p = (bf16*)p; p += SZ_WP;
    float* h  = (float*)p; p += SZ_H;
    bf16* hn  = (bf16*)p; p += SZ_ACT;
    float* part = (float*)p; p += SZ_P;
    float* part1 = part + (size_t)4096 * 1024;
    char* regionA = p;  // aliased: attn-phase buffers, later g
    bf16* xn    = (bf16*)(regionA);
    bf16* qb    = (bf16*)(regionA + 1 * SZ_ACT);
    bf16* kb    = (bf16*)(regionA + 2 * SZ_ACT);
    bf16* vtb   = (bf16*)(regionA + 3 * SZ_ACT);
    bf16* attnb = (bf16*)(regionA + 4 * SZ_ACT);
    bf16* g     = (bf16*)(regionA);   // 27.3 MB; reuses xn..vtb after attention phase

    // 1) prep: all converts (W1/W3 interleaved) + rmsnorm(x)
    prep<<<dim3(15872), dim3(256), 0, stream>>>(wq_w, wk_w, wv_w, wo_w, Wq, Wk, Wv, Wo,
                                                w1_w, w3_w, Wfp, w2_w, W2p,
                                                x, seq_norm_w, xn);

    // 2) QKV projections; q,k head-normed; v transposed
    gemm_qkv<<<dim3(32, 8, 3), dim3(256), 0, stream>>>(xn, Wq, Wk, Wv, wq_b, wk_b, wv_b,
                                                       q_norm_w, k_norm_w, qb, kb, vtb);

    // 3) windowed causal attention (fixed-max softmax)
    attn_win<<<dim3(16, 16, 4), dim3(256), 0, stream>>>(qb, kb, vtb, winp, attnb);

    // 4) O-projection: 256x128 split-K=2 -> f32 partials (K=1024, Kh=512)
    gemm_sk2<<<dim3(16, 8, 2), dim3(512), 0, stream>>>(attnb, Wo, part, 1024, 512);

    // 5) h = x + rmsnorm(p0+p1+wo_b, seq_post); hn = rmsnorm(h, ffn_norm)
    resid_norm<true><<<dim3(512), dim3(512), 0, stream>>>(x, part, part1, wo_b,
                                                          seq_post_norm_w, ffn_norm_w, h, hn);

    // 6) fused FFN1 v3: rotated 4-phase pipeline, swiglu epilogue
    gemm_ffn1_8ph<<<dim3(416), dim3(512), 0, stream>>>(hn, Wfp, w1_b, w3_b, g);

    // 7) FFN2: 256x128 split-K=2 -> f32 partials (K=3328, Kh=1664, 52 iters)
    gemm_sk2<<<dim3(16, 8, 2), dim3(512), 0, stream>>>(g, W2p, part, 3328, 1664);

    // 8) out = h + rmsnorm(p0+p1+w2_b, ffn_post)
    resid_norm<false><<<dim3(512), dim3(512), 0, stream>>>(h, part, part1, w2_b,
                                                           ffn_post_norm_w, nullptr, out, nullptr);
}